// Round 1
// baseline (4178.288 us; speedup 1.0000x reference)
//
#include <hip/hip_runtime.h>
#include <stdint.h>

#define NN   10000
#define NE   320000
#define HID  256
#define EPT  8

__device__ __forceinline__ float silu_f(float v){ return v / (1.f + __expf(-v)); }
__device__ __forceinline__ float sigm_f(float v){ return 1.f / (1.f + __expf(-v)); }
__device__ __forceinline__ float bf2f(unsigned short u){
    return __uint_as_float(((unsigned int)u) << 16);
}

// ---- CSR build -------------------------------------------------------------
__global__ __launch_bounds__(256) void k_count(const int* __restrict__ row, int* __restrict__ cnt){
    int e = blockIdx.x * 256 + threadIdx.x;
    if (e < NE) atomicAdd(&cnt[row[e]], 1);
}

// single block, 256 threads: exclusive scan of cnt[0..NN) -> rs, also copy to cur
__global__ __launch_bounds__(256) void k_scan(const int* __restrict__ cnt, int* __restrict__ rs, int* __restrict__ cur){
    __shared__ int sums[256];
    const int PER = 40;                 // 256*40 = 10240 >= NN
    int t = threadIdx.x;
    int base = t * PER;
    int s = 0;
    for (int i = 0; i < PER; i++){
        int idx = base + i;
        s += (idx < NN) ? cnt[idx] : 0;
    }
    sums[t] = s;
    __syncthreads();
    for (int off = 1; off < 256; off <<= 1){
        int v = (t >= off) ? sums[t - off] : 0;
        __syncthreads();
        sums[t] += v;
        __syncthreads();
    }
    int run = (t == 0) ? 0 : sums[t - 1];
    for (int i = 0; i < PER; i++){
        int idx = base + i;
        if (idx < NN){
            int c = cnt[idx];
            rs[idx] = run;
            cur[idx] = run;
            run += c;
        }
    }
    if (t == 255) rs[NN] = sums[255];
}

__global__ __launch_bounds__(256) void k_fill(const int* __restrict__ row, int* __restrict__ cur, int* __restrict__ perm){
    int e = blockIdx.x * 256 + threadIdx.x;
    if (e < NE){
        int p = atomicAdd(&cur[row[e]], 1);
        perm[p] = e;
    }
}

// ---- convert the three 256x256 "W2" matrices to bf16 in ws -----------------
__global__ __launch_bounds__(256) void k_cvt(const float* __restrict__ a, const float* __restrict__ b,
                                             const float* __restrict__ c, unsigned short* __restrict__ dst){
    int i = blockIdx.x * 256 + threadIdx.x;          // [0, 3*65536)
    const float* src = (i < 65536) ? a : ((i < 131072) ? b : c);
    float f = src[i & 65535];
    unsigned int bits = __float_as_uint(f);
    unsigned int r = (bits + 0x7FFF + ((bits >> 16) & 1)) >> 16;   // RNE
    dst[i] = (unsigned short)r;
}

// ---- generic dense GEMM: C = [R +] act( A1@W1 (+ A2@W2) + bias ) ----------
// A1,A2: [NN,256]  W: [256,256]  block: 256 thr, 16 rows/block, grid 625
__global__ __launch_bounds__(256) void k_gemm(const float* __restrict__ A1, const float* __restrict__ W1,
                                              const float* __restrict__ A2, const float* __restrict__ W2,
                                              const float* __restrict__ bias, const float* __restrict__ R,
                                              float* __restrict__ C, int act){
    __shared__ float at[16][HID];
    int j  = threadIdx.x;
    int rb = blockIdx.x * 16;
    float acc[16];
    float b = bias ? bias[j] : 0.f;
    #pragma unroll
    for (int i = 0; i < 16; i++) acc[i] = b;

    #pragma unroll
    for (int i = 0; i < 16; i++) at[i][j] = A1[(size_t)(rb + i) * HID + j];
    __syncthreads();
    for (int k = 0; k < HID; k += 4){
        float w0 = W1[(k + 0) * HID + j];
        float w1 = W1[(k + 1) * HID + j];
        float w2 = W1[(k + 2) * HID + j];
        float w3 = W1[(k + 3) * HID + j];
        #pragma unroll
        for (int i = 0; i < 16; i++){
            const float4 a4 = *(const float4*)(&at[i][k]);
            acc[i] += a4.x * w0 + a4.y * w1 + a4.z * w2 + a4.w * w3;
        }
    }
    if (A2){
        __syncthreads();
        #pragma unroll
        for (int i = 0; i < 16; i++) at[i][j] = A2[(size_t)(rb + i) * HID + j];
        __syncthreads();
        for (int k = 0; k < HID; k += 4){
            float w0 = W2[(k + 0) * HID + j];
            float w1 = W2[(k + 1) * HID + j];
            float w2 = W2[(k + 2) * HID + j];
            float w3 = W2[(k + 3) * HID + j];
            #pragma unroll
            for (int i = 0; i < 16; i++){
                const float4 a4 = *(const float4*)(&at[i][k]);
                acc[i] += a4.x * w0 + a4.y * w1 + a4.z * w2 + a4.w * w3;
            }
        }
    }
    #pragma unroll
    for (int i = 0; i < 16; i++){
        float v = acc[i];
        if (act) v = silu_f(v);
        if (R) v += R[(size_t)(rb + i) * HID + j];
        C[(size_t)(rb + i) * HID + j] = v;
    }
}

// ---- GCL edge kernel: one block per node ----------------------------------
// v      = silu(Hrow[n] + Hcol[c] + ea@tail)          (Hrow includes eb1)
// mij    = silu(v @ W2bf + eb2)
// att    = sigmoid(mij . aw + ab)
// agg[n] = 0.01 * sum_e mij*att
__global__ __launch_bounds__(256) void k_edge(const float* __restrict__ Hrow, const float* __restrict__ Hcol,
                                              const int* __restrict__ col, const float* __restrict__ ea,
                                              const int* __restrict__ perm, const int* __restrict__ rs,
                                              const unsigned short* __restrict__ w2,
                                              const float* __restrict__ w512, const float* __restrict__ w513,
                                              const float* __restrict__ eb2,
                                              const float* __restrict__ aw, const float* __restrict__ ab,
                                              float* __restrict__ agg){
    __shared__ float vlds[EPT][HID];
    __shared__ float red[4][EPT];
    __shared__ int   ec[EPT];
    __shared__ float ea0[EPT], ea1[EPT];
    __shared__ int   ev[EPT];

    int n = blockIdx.x, j = threadIdx.x;
    float hr  = Hrow[(size_t)n * HID + j];
    float w5  = w512[j], w6 = w513[j], b2 = eb2[j], awj = aw[j];
    float ab0 = ab[0];
    int s = rs[n], e_end = rs[n + 1];
    float aggacc = 0.f;

    for (int t = s; t < e_end; t += EPT){
        if (j < EPT){
            int valid = (t + j) < e_end;
            int eid = valid ? perm[t + j] : 0;
            ec[j]  = valid ? col[eid] : 0;
            ea0[j] = valid ? ea[eid * 2 + 0] : 0.f;
            ea1[j] = valid ? ea[eid * 2 + 1] : 0.f;
            ev[j]  = valid;
        }
        __syncthreads();
        #pragma unroll
        for (int e = 0; e < EPT; e++){
            float v = 0.f;
            if (ev[e]) v = silu_f(hr + Hcol[(size_t)ec[e] * HID + j] + ea0[e] * w5 + ea1[e] * w6);
            vlds[e][j] = v;
        }
        __syncthreads();
        float acc[EPT];
        #pragma unroll
        for (int e = 0; e < EPT; e++) acc[e] = 0.f;
        for (int k = 0; k < HID; k += 4){
            float w0 = bf2f(w2[(k + 0) * HID + j]);
            float w1 = bf2f(w2[(k + 1) * HID + j]);
            float wv2 = bf2f(w2[(k + 2) * HID + j]);
            float w3 = bf2f(w2[(k + 3) * HID + j]);
            #pragma unroll
            for (int e = 0; e < EPT; e++){
                const float4 v4 = *(const float4*)(&vlds[e][k]);
                acc[e] += v4.x * w0 + v4.y * w1 + v4.z * wv2 + v4.w * w3;
            }
        }
        float mij[EPT], part[EPT];
        #pragma unroll
        for (int e = 0; e < EPT; e++){
            mij[e]  = silu_f(acc[e] + b2);
            part[e] = mij[e] * awj;
        }
        #pragma unroll
        for (int e = 0; e < EPT; e++){
            for (int o = 32; o > 0; o >>= 1) part[e] += __shfl_down(part[e], o, 64);
        }
        if ((j & 63) == 0){
            int wv = j >> 6;
            #pragma unroll
            for (int e = 0; e < EPT; e++) red[wv][e] = part[e];
        }
        __syncthreads();
        #pragma unroll
        for (int e = 0; e < EPT; e++){
            if (ev[e]){
                float sm  = red[0][e] + red[1][e] + red[2][e] + red[3][e];
                float att = sigm_f(sm + ab0);
                aggacc += mij[e] * att;
            }
        }
        __syncthreads();
    }
    agg[(size_t)n * HID + j] = aggacc * 0.01f;   // /NORM_FACTOR folded in
}

// ---- coord edge kernel: one block per node --------------------------------
// u   = silu(Crow[n] + Ccol[c] + ea@tail)  (Crow includes cb1)
// phi = silu(u @ W2bf + cb2) . cw3
// x_out[n] = x[n] + 0.01 * sum_e coord_diff(e) * phi(e)
__global__ __launch_bounds__(256) void k_coord(const float* __restrict__ Crow, const float* __restrict__ Ccol,
                                               const int* __restrict__ col, const float* __restrict__ ea,
                                               const int* __restrict__ perm, const int* __restrict__ rs,
                                               const unsigned short* __restrict__ w2,
                                               const float* __restrict__ w512, const float* __restrict__ w513,
                                               const float* __restrict__ cb2, const float* __restrict__ cw3,
                                               const float* __restrict__ x, float* __restrict__ xout){
    __shared__ float vlds[EPT][HID];
    __shared__ float red[4][EPT];
    __shared__ float xred[EPT][3];
    __shared__ int   ec[EPT];
    __shared__ float ea0[EPT], ea1[EPT];
    __shared__ int   ev[EPT];

    int n = blockIdx.x, j = threadIdx.x;
    float hr = Crow[(size_t)n * HID + j];
    float w5 = w512[j], w6 = w513[j], b2 = cb2[j], w3j = cw3[j];
    float xn0 = x[n * 3 + 0], xn1 = x[n * 3 + 1], xn2 = x[n * 3 + 2];
    int s = rs[n], e_end = rs[n + 1];
    float tx = 0.f, ty = 0.f, tz = 0.f;

    for (int t = s; t < e_end; t += EPT){
        if (j < EPT){
            int valid = (t + j) < e_end;
            int eid = valid ? perm[t + j] : 0;
            ec[j]  = valid ? col[eid] : 0;
            ea0[j] = valid ? ea[eid * 2 + 0] : 0.f;
            ea1[j] = valid ? ea[eid * 2 + 1] : 0.f;
            ev[j]  = valid;
        }
        __syncthreads();
        #pragma unroll
        for (int e = 0; e < EPT; e++){
            float v = 0.f;
            if (ev[e]) v = silu_f(hr + Ccol[(size_t)ec[e] * HID + j] + ea0[e] * w5 + ea1[e] * w6);
            vlds[e][j] = v;
        }
        __syncthreads();
        float acc[EPT];
        #pragma unroll
        for (int e = 0; e < EPT; e++) acc[e] = 0.f;
        for (int k = 0; k < HID; k += 4){
            float w0 = bf2f(w2[(k + 0) * HID + j]);
            float w1 = bf2f(w2[(k + 1) * HID + j]);
            float wv2 = bf2f(w2[(k + 2) * HID + j]);
            float w3 = bf2f(w2[(k + 3) * HID + j]);
            #pragma unroll
            for (int e = 0; e < EPT; e++){
                const float4 v4 = *(const float4*)(&vlds[e][k]);
                acc[e] += v4.x * w0 + v4.y * w1 + v4.z * wv2 + v4.w * w3;
            }
        }
        float part[EPT];
        #pragma unroll
        for (int e = 0; e < EPT; e++) part[e] = silu_f(acc[e] + b2) * w3j;
        #pragma unroll
        for (int e = 0; e < EPT; e++){
            for (int o = 32; o > 0; o >>= 1) part[e] += __shfl_down(part[e], o, 64);
        }
        if ((j & 63) == 0){
            int wv = j >> 6;
            #pragma unroll
            for (int e = 0; e < EPT; e++) red[wv][e] = part[e];
        }
        __syncthreads();
        if (j < EPT && ev[j]){
            float phi = red[0][j] + red[1][j] + red[2][j] + red[3][j];   // cw3 has no bias
            int c = ec[j];
            float d0 = xn0 - x[c * 3 + 0];
            float d1 = xn1 - x[c * 3 + 1];
            float d2 = xn2 - x[c * 3 + 2];
            float r2 = d0 * d0 + d1 * d1 + d2 * d2;
            float f  = phi / (sqrtf(r2 + 1e-8f) + 1.f);   // NORM_CONST = 1
            tx += d0 * f; ty += d1 * f; tz += d2 * f;
        }
        __syncthreads();
    }
    if (j < EPT){ xred[j][0] = tx; xred[j][1] = ty; xred[j][2] = tz; }
    __syncthreads();
    if (j < 3){
        float sj = 0.f;
        #pragma unroll
        for (int e = 0; e < EPT; e++) sj += xred[e][j];
        xout[n * 3 + j] = x[n * 3 + j] + sj * 0.01f;
    }
}

// ---------------------------------------------------------------------------
extern "C" void kernel_launch(void* const* d_in, const int* in_sizes, int n_in,
                              void* d_out, int out_size, void* d_ws, size_t ws_size,
                              hipStream_t stream){
    const float* h  = (const float*)d_in[0];
    const float* x  = (const float*)d_in[1];
    const int*   ei = (const int*)d_in[2];
    const float* ea = (const float*)d_in[3];
    const int* row  = ei;
    const int* colp = ei + NE;

    const float* ew1[2] = {(const float*)d_in[4],  (const float*)d_in[14]};
    const float* eb1[2] = {(const float*)d_in[5],  (const float*)d_in[15]};
    const float* ew2[2] = {(const float*)d_in[6],  (const float*)d_in[16]};
    const float* eb2[2] = {(const float*)d_in[7],  (const float*)d_in[17]};
    const float* nw1[2] = {(const float*)d_in[8],  (const float*)d_in[18]};
    const float* nb1[2] = {(const float*)d_in[9],  (const float*)d_in[19]};
    const float* nw2[2] = {(const float*)d_in[10], (const float*)d_in[20]};
    const float* nb2[2] = {(const float*)d_in[11], (const float*)d_in[21]};
    const float* aw[2]  = {(const float*)d_in[12], (const float*)d_in[22]};
    const float* ab[2]  = {(const float*)d_in[13], (const float*)d_in[23]};
    const float* cw1 = (const float*)d_in[24];
    const float* cb1 = (const float*)d_in[25];
    const float* cw2 = (const float*)d_in[26];
    const float* cb2 = (const float*)d_in[27];
    const float* cw3 = (const float*)d_in[28];

    char* w = (char*)d_ws;
    auto alloc = [&](size_t bytes){ void* p = (void*)w; w += (bytes + 255) & ~((size_t)255); return p; };
    int* rs    = (int*)alloc((NN + 1) * sizeof(int));
    int* cur   = (int*)alloc(NN * sizeof(int));
    int* perm  = (int*)alloc(NE * sizeof(int));
    float* Hrow = (float*)alloc((size_t)NN * HID * sizeof(float));
    float* Hcol = (float*)alloc((size_t)NN * HID * sizeof(float));
    float* aggb = (float*)alloc((size_t)NN * HID * sizeof(float));
    unsigned short* w2bf = (unsigned short*)alloc((size_t)3 * HID * HID * sizeof(unsigned short));
    float* Tb = Hrow;   // dead after k_edge; reuse for node-MLP hidden

    float* hout = (float*)d_out;          // [NN,HID]
    float* xout = hout + (size_t)NN * HID; // [NN,3]

    // CSR build (per-call; inputs restored each call)
    hipMemsetAsync(cur, 0, NN * sizeof(int), stream);
    k_count<<<(NE + 255) / 256, 256, 0, stream>>>(row, cur);
    k_scan<<<1, 256, 0, stream>>>(cur, rs, cur);
    k_fill<<<(NE + 255) / 256, 256, 0, stream>>>(row, cur, perm);
    k_cvt<<<768, 256, 0, stream>>>(ew2[0], ew2[1], cw2, w2bf);

    const float* hcur = h;
    for (int l = 0; l < 2; l++){
        // Hrow = h@ew1[0:256] + eb1 ; Hcol = h@ew1[256:512]
        k_gemm<<<625, 256, 0, stream>>>(hcur, ew1[l],              nullptr, nullptr, eb1[l], nullptr, Hrow, 0);
        k_gemm<<<625, 256, 0, stream>>>(hcur, ew1[l] + 256 * HID,  nullptr, nullptr, nullptr, nullptr, Hcol, 0);
        k_edge<<<NN, 256, 0, stream>>>(Hrow, Hcol, colp, ea, perm, rs,
                                       w2bf + (size_t)l * HID * HID,
                                       ew1[l] + 512 * HID, ew1[l] + 513 * HID,
                                       eb2[l], aw[l], ab[l], aggb);
        // T = silu(h@nw1[0:256] + agg@nw1[256:512] + nb1) ; h = h + T@nw2 + nb2
        k_gemm<<<625, 256, 0, stream>>>(hcur, nw1[l], aggb, nw1[l] + 256 * HID, nb1[l], nullptr, Tb, 1);
        k_gemm<<<625, 256, 0, stream>>>(Tb, nw2[l], nullptr, nullptr, nb2[l], hcur, hout, 0);
        hcur = hout;
    }
    // coord update
    k_gemm<<<625, 256, 0, stream>>>(hout, cw1,             nullptr, nullptr, cb1, nullptr, Hcol, 0);
    // NOTE: Hcol currently holds Crow; reuse aggb for Ccol (both dead now)
    k_gemm<<<625, 256, 0, stream>>>(hout, cw1 + 256 * HID, nullptr, nullptr, nullptr, nullptr, aggb, 0);
    k_coord<<<NN, 256, 0, stream>>>(Hcol, aggb, colp, ea, perm, rs,
                                    w2bf + (size_t)2 * HID * HID,
                                    cw1 + 512 * HID, cw1 + 513 * HID,
                                    cb2, cw3, x, xout);
}

// Round 2
// 1288.771 us; speedup vs baseline: 3.2421x; 3.2421x over previous
//
#include <hip/hip_runtime.h>
#include <stdint.h>

#define NN   10000
#define NE   320000
#define HID  256
#define MB   128                 // edges per block in MFMA edge kernels
#define NEB  (NE/MB)             // 2500 blocks (exact)
#define VST  264                 // LDS row stride in bf16 elems (528 B: 2-way conflict max on b128)

typedef __attribute__((ext_vector_type(8))) short short8;
typedef __attribute__((ext_vector_type(4))) float f32x4;

__device__ __forceinline__ float silu_f(float v){ return v / (1.f + __expf(-v)); }
__device__ __forceinline__ float sigm_f(float v){ return 1.f / (1.f + __expf(-v)); }
__device__ __forceinline__ float bf2f(unsigned short u){
    return __uint_as_float(((unsigned int)u) << 16);
}
__device__ __forceinline__ unsigned short f2bf(float f){
    unsigned int b = __float_as_uint(f);
    return (unsigned short)((b + 0x7FFF + ((b >> 16) & 1)) >> 16);   // RNE
}

// ---- CSR build -------------------------------------------------------------
__global__ __launch_bounds__(256) void k_count(const int* __restrict__ row, int* __restrict__ cnt){
    int e = blockIdx.x * 256 + threadIdx.x;
    if (e < NE) atomicAdd(&cnt[row[e]], 1);
}

__global__ __launch_bounds__(256) void k_scan(const int* __restrict__ cnt, int* __restrict__ rs, int* __restrict__ cur){
    __shared__ int sums[256];
    const int PER = 40;
    int t = threadIdx.x;
    int base = t * PER;
    int s = 0;
    for (int i = 0; i < PER; i++){
        int idx = base + i;
        s += (idx < NN) ? cnt[idx] : 0;
    }
    sums[t] = s;
    __syncthreads();
    for (int off = 1; off < 256; off <<= 1){
        int v = (t >= off) ? sums[t - off] : 0;
        __syncthreads();
        sums[t] += v;
        __syncthreads();
    }
    int run = (t == 0) ? 0 : sums[t - 1];
    for (int i = 0; i < PER; i++){
        int idx = base + i;
        if (idx < NN){
            int c = cnt[idx];
            rs[idx] = run;
            cur[idx] = run;
            run += c;
        }
    }
    if (t == 255) rs[NN] = sums[255];
}

__global__ __launch_bounds__(256) void k_fill(const int* __restrict__ row, int* __restrict__ cur, int* __restrict__ perm){
    int e = blockIdx.x * 256 + threadIdx.x;
    if (e < NE){
        int p = atomicAdd(&cur[row[e]], 1);
        perm[p] = e;
    }
}

// ---- W2 matrices -> bf16, MFMA-B-fragment order ---------------------------
// dst linear idx = m*65536 + ((nt*8 + kk)*64 + lane)*8 + j
// value = W2[k][n] with k = kk*32+(lane>>4)*8+j, n = nt*16+(lane&15)
__global__ __launch_bounds__(256) void k_cvt(const float* __restrict__ a, const float* __restrict__ b,
                                             const float* __restrict__ c, unsigned short* __restrict__ dst){
    int i = blockIdx.x * 256 + threadIdx.x;          // [0, 3*65536)
    const float* src = (i < 65536) ? a : ((i < 131072) ? b : c);
    int t = i & 65535;
    int j = t & 7, lane = (t >> 3) & 63, kk = (t >> 9) & 7, nt = t >> 12;
    int k = kk * 32 + (lane >> 4) * 8 + j;
    int n = nt * 16 + (lane & 15);
    dst[i] = f2bf(src[k * HID + n]);
}

// ---- dense node GEMM (VALU): C = [R +] act( A1@W1 (+ A2@W2) + bias ) ------
__global__ __launch_bounds__(256) void k_gemm(const float* __restrict__ A1, const float* __restrict__ W1,
                                              const float* __restrict__ A2, const float* __restrict__ W2,
                                              const float* __restrict__ bias, const float* __restrict__ R,
                                              float* __restrict__ C, int act, int obf){
    __shared__ float at[16][HID];
    int j  = threadIdx.x;
    int rb = blockIdx.x * 16;
    float acc[16];
    float b = bias ? bias[j] : 0.f;
    #pragma unroll
    for (int i = 0; i < 16; i++) acc[i] = b;

    #pragma unroll
    for (int i = 0; i < 16; i++) at[i][j] = A1[(size_t)(rb + i) * HID + j];
    __syncthreads();
    for (int k = 0; k < HID; k += 4){
        float w0 = W1[(k + 0) * HID + j];
        float w1 = W1[(k + 1) * HID + j];
        float w2 = W1[(k + 2) * HID + j];
        float w3 = W1[(k + 3) * HID + j];
        #pragma unroll
        for (int i = 0; i < 16; i++){
            const float4 a4 = *(const float4*)(&at[i][k]);
            acc[i] += a4.x * w0 + a4.y * w1 + a4.z * w2 + a4.w * w3;
        }
    }
    if (A2){
        __syncthreads();
        #pragma unroll
        for (int i = 0; i < 16; i++) at[i][j] = A2[(size_t)(rb + i) * HID + j];
        __syncthreads();
        for (int k = 0; k < HID; k += 4){
            float w0 = W2[(k + 0) * HID + j];
            float w1 = W2[(k + 1) * HID + j];
            float w2 = W2[(k + 2) * HID + j];
            float w3 = W2[(k + 3) * HID + j];
            #pragma unroll
            for (int i = 0; i < 16; i++){
                const float4 a4 = *(const float4*)(&at[i][k]);
                acc[i] += a4.x * w0 + a4.y * w1 + a4.z * w2 + a4.w * w3;
            }
        }
    }
    #pragma unroll
    for (int i = 0; i < 16; i++){
        float v = acc[i];
        if (act) v = silu_f(v);
        if (R) v += R[(size_t)(rb + i) * HID + j];
        size_t idx = (size_t)(rb + i) * HID + j;
        if (obf) ((unsigned short*)C)[idx] = f2bf(v);
        else     C[idx] = v;
    }
}

// ---- MFMA edge kernel (GCL): 128 perm-ordered edges per block -------------
// v   = silu(HrowB[n] + HcolB[c] + ea@tail)     (HrowB includes eb1, bf16)
// mij = silu(v @ W2 + eb2)   via mfma_f32_16x16x32_bf16
// att = sigmoid(mij . aw + ab);  agg[n] += 0.01 * sum mij*att  (atomics)
__global__ __launch_bounds__(256, 2) void k_edge_mfma(
        const unsigned short* __restrict__ HrowB, const unsigned short* __restrict__ HcolB,
        const int* __restrict__ row, const int* __restrict__ col,
        const float* __restrict__ ea, const int* __restrict__ perm,
        const unsigned short* __restrict__ w2f,
        const float* __restrict__ w512, const float* __restrict__ w513,
        const float* __restrict__ eb2, const float* __restrict__ aw, const float* __restrict__ ab,
        float* __restrict__ agg){
    __shared__ unsigned short vlds[MB * VST];
    __shared__ float attp[4][MB];
    __shared__ float attf[MB];
    __shared__ int   nrows[MB];
    __shared__ int   cids[MB];
    __shared__ float ea0s[MB], ea1s[MB];

    int tid = threadIdx.x;
    int e0  = blockIdx.x * MB;
    if (tid < MB){
        int eid = perm[e0 + tid];
        nrows[tid] = row[eid];
        cids[tid]  = col[eid];
        ea0s[tid]  = ea[eid * 2 + 0];
        ea1s[tid]  = ea[eid * 2 + 1];
    }
    __syncthreads();
    {   // v-compute: thread tid owns column tid
        float w5 = w512[tid], w6 = w513[tid];
        #pragma unroll 4
        for (int r = 0; r < MB; r++){
            int nid = nrows[r], cid = cids[r];
            float v = bf2f(HrowB[(size_t)nid * HID + tid]) + bf2f(HcolB[(size_t)cid * HID + tid])
                    + ea0s[r] * w5 + ea1s[r] * w6;
            vlds[r * VST + tid] = f2bf(silu_f(v));
        }
    }
    __syncthreads();

    int lid = tid & 63, w = tid >> 6;
    int quad = lid >> 4, l15 = lid & 15;

    f32x4 acc[8][4];
    #pragma unroll
    for (int m = 0; m < 8; m++)
        #pragma unroll
        for (int n = 0; n < 4; n++){ f32x4 z = {0.f, 0.f, 0.f, 0.f}; acc[m][n] = z; }

    const short8* bbase = (const short8*)w2f;
    #pragma unroll
    for (int kk = 0; kk < 8; kk++){
        short8 bf[4];
        #pragma unroll
        for (int n = 0; n < 4; n++)
            bf[n] = bbase[((w * 4 + n) * 8 + kk) * 64 + lid];
        #pragma unroll
        for (int m = 0; m < 8; m++){
            const short8 af = *(const short8*)&vlds[(m * 16 + l15) * VST + kk * 32 + quad * 8];
            #pragma unroll
            for (int n = 0; n < 4; n++)
                acc[m][n] = __builtin_amdgcn_mfma_f32_16x16x32_bf16(af, bf[n], acc[m][n], 0, 0, 0);
        }
    }

    // epilogue: mij = silu(acc+eb2); attention row-dot partials
    float b2v[4], awv[4];
    #pragma unroll
    for (int n = 0; n < 4; n++){
        int cg = w * 64 + n * 16 + l15;
        b2v[n] = eb2[cg]; awv[n] = aw[cg];
    }
    #pragma unroll
    for (int m = 0; m < 8; m++){
        float p[4] = {0.f, 0.f, 0.f, 0.f};
        #pragma unroll
        for (int n = 0; n < 4; n++){
            #pragma unroll
            for (int r = 0; r < 4; r++){
                float mij = silu_f(acc[m][n][r] + b2v[n]);
                acc[m][n][r] = mij;
                p[r] += mij * awv[n];
            }
        }
        #pragma unroll
        for (int r = 0; r < 4; r++){
            p[r] += __shfl_xor(p[r], 1);
            p[r] += __shfl_xor(p[r], 2);
            p[r] += __shfl_xor(p[r], 4);
            p[r] += __shfl_xor(p[r], 8);
        }
        if (l15 == 0){
            #pragma unroll
            for (int r = 0; r < 4; r++)
                attp[w][m * 16 + quad * 4 + r] = p[r];
        }
    }
    __syncthreads();
    if (tid < MB){
        float a0 = attp[0][tid] + attp[1][tid] + attp[2][tid] + attp[3][tid] + ab[0];
        attf[tid] = 0.01f * sigm_f(a0);     // fold /NORM_FACTOR into att
    }
    __syncthreads();

    // segment-sum agg via per-segment reduced atomics (rows are CSR-sorted)
    for (int m = 0; m < 8; m++){
        int mb = m * 16;
        float av[4]; int nv[4];
        #pragma unroll
        for (int r = 0; r < 4; r++){
            av[r] = attf[mb + quad * 4 + r];
            nv[r] = nrows[mb + quad * 4 + r];
        }
        float ef[4][4];
        #pragma unroll
        for (int n = 0; n < 4; n++)
            #pragma unroll
            for (int r = 0; r < 4; r++)
                ef[n][r] = acc[m][n][r] * av[r];

        int myn = nrows[mb + l15];          // valid LDS addr for every lane
        int t16 = 0;
        while (t16 < 16){
            int tgt = nrows[mb + t16];
            unsigned long long bal = __ballot((lid < 16) && (lid > t16) && (myn != tgt));
            int nxt = bal ? (__ffsll((unsigned long long)bal) - 1) : 16;
            bool whole = (t16 == 0) && (nxt == 16);
            #pragma unroll
            for (int n = 0; n < 4; n++){
                float s = 0.f;
                #pragma unroll
                for (int r = 0; r < 4; r++)
                    s += (whole || nv[r] == tgt) ? ef[n][r] : 0.f;
                s += __shfl_xor(s, 16);
                s += __shfl_xor(s, 32);
                if (lid < 16)
                    atomicAdd(&agg[(size_t)tgt * HID + w * 64 + n * 16 + lid], s);
            }
            t16 = nxt;
        }
    }
}

// ---- MFMA coord kernel: same GEMM, epilogue -> per-edge phi ---------------
__global__ __launch_bounds__(256, 2) void k_coord_mfma(
        const unsigned short* __restrict__ CrowB, const unsigned short* __restrict__ CcolB,
        const int* __restrict__ row, const int* __restrict__ col,
        const float* __restrict__ ea, const int* __restrict__ perm,
        const unsigned short* __restrict__ w2f,
        const float* __restrict__ w512, const float* __restrict__ w513,
        const float* __restrict__ cb2, const float* __restrict__ cw3,
        float* __restrict__ phi){
    __shared__ unsigned short vlds[MB * VST];
    __shared__ float pp[4][MB];
    __shared__ int   nrows[MB];
    __shared__ int   cids[MB];
    __shared__ float ea0s[MB], ea1s[MB];

    int tid = threadIdx.x;
    int e0  = blockIdx.x * MB;
    if (tid < MB){
        int eid = perm[e0 + tid];
        nrows[tid] = row[eid];
        cids[tid]  = col[eid];
        ea0s[tid]  = ea[eid * 2 + 0];
        ea1s[tid]  = ea[eid * 2 + 1];
    }
    __syncthreads();
    {
        float w5 = w512[tid], w6 = w513[tid];
        #pragma unroll 4
        for (int r = 0; r < MB; r++){
            int nid = nrows[r], cid = cids[r];
            float v = bf2f(CrowB[(size_t)nid * HID + tid]) + bf2f(CcolB[(size_t)cid * HID + tid])
                    + ea0s[r] * w5 + ea1s[r] * w6;
            vlds[r * VST + tid] = f2bf(silu_f(v));
        }
    }
    __syncthreads();

    int lid = tid & 63, w = tid >> 6;
    int quad = lid >> 4, l15 = lid & 15;

    f32x4 acc[8][4];
    #pragma unroll
    for (int m = 0; m < 8; m++)
        #pragma unroll
        for (int n = 0; n < 4; n++){ f32x4 z = {0.f, 0.f, 0.f, 0.f}; acc[m][n] = z; }

    const short8* bbase = (const short8*)w2f;
    #pragma unroll
    for (int kk = 0; kk < 8; kk++){
        short8 bf[4];
        #pragma unroll
        for (int n = 0; n < 4; n++)
            bf[n] = bbase[((w * 4 + n) * 8 + kk) * 64 + lid];
        #pragma unroll
        for (int m = 0; m < 8; m++){
            const short8 af = *(const short8*)&vlds[(m * 16 + l15) * VST + kk * 32 + quad * 8];
            #pragma unroll
            for (int n = 0; n < 4; n++)
                acc[m][n] = __builtin_amdgcn_mfma_f32_16x16x32_bf16(af, bf[n], acc[m][n], 0, 0, 0);
        }
    }

    float b2v[4], w3v[4];
    #pragma unroll
    for (int n = 0; n < 4; n++){
        int cg = w * 64 + n * 16 + l15;
        b2v[n] = cb2[cg]; w3v[n] = cw3[cg];
    }
    #pragma unroll
    for (int m = 0; m < 8; m++){
        float p[4] = {0.f, 0.f, 0.f, 0.f};
        #pragma unroll
        for (int n = 0; n < 4; n++)
            #pragma unroll
            for (int r = 0; r < 4; r++)
                p[r] += silu_f(acc[m][n][r] + b2v[n]) * w3v[n];
        #pragma unroll
        for (int r = 0; r < 4; r++){
            p[r] += __shfl_xor(p[r], 1);
            p[r] += __shfl_xor(p[r], 2);
            p[r] += __shfl_xor(p[r], 4);
            p[r] += __shfl_xor(p[r], 8);
        }
        if (l15 == 0){
            #pragma unroll
            for (int r = 0; r < 4; r++)
                pp[w][m * 16 + quad * 4 + r] = p[r];
        }
    }
    __syncthreads();
    if (tid < MB)
        phi[e0 + tid] = pp[0][tid] + pp[1][tid] + pp[2][tid] + pp[3][tid];
}

// ---- coordinate segment-sum: one wave per node ----------------------------
__global__ __launch_bounds__(64) void k_xupd(const float* __restrict__ x, const float* __restrict__ phi,
                                             const int* __restrict__ col, const int* __restrict__ perm,
                                             const int* __restrict__ rs, float* __restrict__ xout){
    int n = blockIdx.x, lid = threadIdx.x;
    int s = rs[n], e = rs[n + 1];
    float x0 = x[n * 3 + 0], x1 = x[n * 3 + 1], x2 = x[n * 3 + 2];
    float tx = 0.f, ty = 0.f, tz = 0.f;
    for (int i = s + lid; i < e; i += 64){
        int eid = perm[i];
        int c = col[eid];
        float d0 = x0 - x[c * 3 + 0];
        float d1 = x1 - x[c * 3 + 1];
        float d2 = x2 - x[c * 3 + 2];
        float r2 = d0 * d0 + d1 * d1 + d2 * d2;
        float f  = phi[i] / (sqrtf(r2 + 1e-8f) + 1.f);   // NORM_CONST = 1
        tx += d0 * f; ty += d1 * f; tz += d2 * f;
    }
    for (int o = 32; o; o >>= 1){
        tx += __shfl_down(tx, o);
        ty += __shfl_down(ty, o);
        tz += __shfl_down(tz, o);
    }
    if (lid == 0){
        xout[n * 3 + 0] = x0 + 0.01f * tx;
        xout[n * 3 + 1] = x1 + 0.01f * ty;
        xout[n * 3 + 2] = x2 + 0.01f * tz;
    }
}

// ---------------------------------------------------------------------------
extern "C" void kernel_launch(void* const* d_in, const int* in_sizes, int n_in,
                              void* d_out, int out_size, void* d_ws, size_t ws_size,
                              hipStream_t stream){
    const float* h  = (const float*)d_in[0];
    const float* x  = (const float*)d_in[1];
    const int*   ei = (const int*)d_in[2];
    const float* ea = (const float*)d_in[3];
    const int* rowp = ei;
    const int* colp = ei + NE;

    const float* ew1[2] = {(const float*)d_in[4],  (const float*)d_in[14]};
    const float* eb1[2] = {(const float*)d_in[5],  (const float*)d_in[15]};
    const float* ew2[2] = {(const float*)d_in[6],  (const float*)d_in[16]};
    const float* eb2[2] = {(const float*)d_in[7],  (const float*)d_in[17]};
    const float* nw1[2] = {(const float*)d_in[8],  (const float*)d_in[18]};
    const float* nb1[2] = {(const float*)d_in[9],  (const float*)d_in[19]};
    const float* nw2[2] = {(const float*)d_in[10], (const float*)d_in[20]};
    const float* nb2[2] = {(const float*)d_in[11], (const float*)d_in[21]};
    const float* aw[2]  = {(const float*)d_in[12], (const float*)d_in[22]};
    const float* ab[2]  = {(const float*)d_in[13], (const float*)d_in[23]};
    const float* cw1 = (const float*)d_in[24];
    const float* cb1 = (const float*)d_in[25];
    const float* cw2 = (const float*)d_in[26];
    const float* cb2 = (const float*)d_in[27];
    const float* cw3 = (const float*)d_in[28];

    char* w = (char*)d_ws;
    auto alloc = [&](size_t bytes){ void* p = (void*)w; w += (bytes + 255) & ~((size_t)255); return p; };
    int* rs    = (int*)alloc((NN + 1) * sizeof(int));
    int* cur   = (int*)alloc(NN * sizeof(int));
    int* perm  = (int*)alloc(NE * sizeof(int));
    unsigned short* HrowB = (unsigned short*)alloc((size_t)NN * HID * sizeof(unsigned short));
    unsigned short* HcolB = (unsigned short*)alloc((size_t)NN * HID * sizeof(unsigned short));
    float* aggb = (float*)alloc((size_t)NN * HID * sizeof(float));
    unsigned short* w2f = (unsigned short*)alloc((size_t)3 * HID * HID * sizeof(unsigned short));
    float* phi  = (float*)alloc((size_t)NE * sizeof(float));
    float* Tb   = (float*)HrowB;   // HrowB+HcolB contiguous 10.24 MB, dead when Tb live

    float* hout = (float*)d_out;            // [NN,HID]
    float* xout = hout + (size_t)NN * HID;  // [NN,3]

    // CSR build + weight conversion
    hipMemsetAsync(cur, 0, NN * sizeof(int), stream);
    k_count<<<(NE + 255) / 256, 256, 0, stream>>>(rowp, cur);
    k_scan<<<1, 256, 0, stream>>>(cur, rs, cur);
    k_fill<<<(NE + 255) / 256, 256, 0, stream>>>(rowp, cur, perm);
    k_cvt<<<768, 256, 0, stream>>>(ew2[0], ew2[1], cw2, w2f);

    const float* hcur = h;
    for (int l = 0; l < 2; l++){
        k_gemm<<<625, 256, 0, stream>>>(hcur, ew1[l],             nullptr, nullptr, eb1[l], nullptr, (float*)HrowB, 0, 1);
        k_gemm<<<625, 256, 0, stream>>>(hcur, ew1[l] + 256 * HID, nullptr, nullptr, nullptr, nullptr, (float*)HcolB, 0, 1);
        hipMemsetAsync(aggb, 0, (size_t)NN * HID * sizeof(float), stream);
        k_edge_mfma<<<NEB, 256, 0, stream>>>(HrowB, HcolB, rowp, colp, ea, perm,
                                             w2f + (size_t)l * HID * HID,
                                             ew1[l] + 512 * HID, ew1[l] + 513 * HID,
                                             eb2[l], aw[l], ab[l], aggb);
        k_gemm<<<625, 256, 0, stream>>>(hcur, nw1[l], aggb, nw1[l] + 256 * HID, nb1[l], nullptr, Tb, 1, 0);
        k_gemm<<<625, 256, 0, stream>>>(Tb, nw2[l], nullptr, nullptr, nb2[l], hcur, hout, 0, 0);
        hcur = hout;
    }
    // coord update
    k_gemm<<<625, 256, 0, stream>>>(hout, cw1,             nullptr, nullptr, cb1, nullptr, (float*)HrowB, 0, 1);
    k_gemm<<<625, 256, 0, stream>>>(hout, cw1 + 256 * HID, nullptr, nullptr, nullptr, nullptr, (float*)HcolB, 0, 1);
    k_coord_mfma<<<NEB, 256, 0, stream>>>(HrowB, HcolB, rowp, colp, ea, perm,
                                          w2f + (size_t)2 * HID * HID,
                                          cw1 + 512 * HID, cw1 + 513 * HID,
                                          cb2, cw3, phi);
    k_xupd<<<NN, 64, 0, stream>>>(x, phi, colp, perm, rs, xout);
}

// Round 3
// 729.917 us; speedup vs baseline: 5.7243x; 1.7656x over previous
//
#include <hip/hip_runtime.h>
#include <stdint.h>

#define NN   10000
#define NE   320000
#define HID  256
#define MB   64                  // edges per block in MFMA edge kernels
#define NEB  (NE/MB)             // 5000 blocks (exact)
#define VST  264                 // LDS row stride in bf16 elems

typedef __attribute__((ext_vector_type(8))) short short8;
typedef __attribute__((ext_vector_type(4))) float f32x4;

struct CvtPtrs { const float* p[15]; };

__device__ __forceinline__ float silu_f(float v){ return v / (1.f + __expf(-v)); }
__device__ __forceinline__ float sigm_f(float v){ return 1.f / (1.f + __expf(-v)); }
__device__ __forceinline__ unsigned short f2bf(float f){
    unsigned int b = __float_as_uint(f);
    return (unsigned short)((b + 0x7FFF + ((b >> 16) & 1)) >> 16);   // RNE
}

// ---- CSR build -------------------------------------------------------------
__global__ __launch_bounds__(256) void k_count(const int* __restrict__ row, int* __restrict__ cnt){
    int e = blockIdx.x * 256 + threadIdx.x;
    if (e < NE) atomicAdd(&cnt[row[e]], 1);
}

__global__ __launch_bounds__(256) void k_scan(const int* __restrict__ cnt, int* __restrict__ rs, int* __restrict__ cur){
    __shared__ int sums[256];
    const int PER = 40;
    int t = threadIdx.x;
    int base = t * PER;
    int s = 0;
    for (int i = 0; i < PER; i++){
        int idx = base + i;
        s += (idx < NN) ? cnt[idx] : 0;
    }
    sums[t] = s;
    __syncthreads();
    for (int off = 1; off < 256; off <<= 1){
        int v = (t >= off) ? sums[t - off] : 0;
        __syncthreads();
        sums[t] += v;
        __syncthreads();
    }
    int run = (t == 0) ? 0 : sums[t - 1];
    for (int i = 0; i < PER; i++){
        int idx = base + i;
        if (idx < NN){
            int c = cnt[idx];
            rs[idx] = run;
            cur[idx] = run;
            run += c;
        }
    }
    if (t == 255) rs[NN] = sums[255];
}

__global__ __launch_bounds__(256) void k_fill(const int* __restrict__ row, int* __restrict__ cur, int* __restrict__ perm){
    int e = blockIdx.x * 256 + threadIdx.x;
    if (e < NE){
        int p = atomicAdd(&cur[row[e]], 1);
        perm[p] = e;
    }
}

// ---- convert 15 [256,256] weight chunks -> bf16, MFMA-B-fragment order ----
// dst linear idx (within matrix) = ((nt*8 + kk)*64 + lane)*8 + j
// value = W[k][n] with k = kk*32+(lane>>4)*8+j, n = nt*16+(lane&15)
__global__ __launch_bounds__(256) void k_cvtw(CvtPtrs pp, unsigned short* __restrict__ dst){
    int i = blockIdx.x * 256 + threadIdx.x;          // [0, 15*65536)
    const float* src = pp.p[i >> 16];
    int t = i & 65535;
    int j = t & 7, lane = (t >> 3) & 63, kk = (t >> 9) & 7, nt = t >> 12;
    int k = kk * 32 + (lane >> 4) * 8 + j;
    int n = nt * 16 + (lane & 15);
    dst[i] = f2bf(src[k * HID + n]);
}

// ---- MFMA dense GEMM: C = [R +] act( A1@W1 [+ A2@W2] + bias ) -------------
// A [NN,256] fp32; W from frag-ordered bf16 pool; tile M=64, N=128
// grid (157, 2), block 256
__global__ __launch_bounds__(256, 4) void k_dgemm(
        const float* __restrict__ A1, const float* __restrict__ A2,
        const unsigned short* __restrict__ wpool, int w1idx, int w2idx,
        const float* __restrict__ bias, const float* __restrict__ R,
        void* __restrict__ C, int act, int obf){
    __shared__ unsigned short alds[64 * VST];
    int tid = threadIdx.x;
    int lid = tid & 63, w = tid >> 6;
    int quad = lid >> 4, l15 = lid & 15;
    int rb = blockIdx.x * 64;
    int by = blockIdx.y;

    f32x4 acc[4][2];
    #pragma unroll
    for (int m = 0; m < 4; m++)
        #pragma unroll
        for (int n = 0; n < 2; n++){ f32x4 z = {0.f,0.f,0.f,0.f}; acc[m][n] = z; }

    int npass = A2 ? 2 : 1;
    for (int pass = 0; pass < npass; pass++){
        if (pass) __syncthreads();
        const float* A = pass ? A2 : A1;
        const short8* bbase = (const short8*)(wpool + (size_t)(pass ? w2idx : w1idx) * 65536);
        int sr = tid >> 5, c0 = (tid & 31) * 8;
        for (int it = 0; it < 8; it++){
            int r = it * 8 + sr;
            int rr = rb + r; if (rr > NN - 1) rr = NN - 1;
            float4 f0 = *(const float4*)&A[(size_t)rr * HID + c0];
            float4 f1 = *(const float4*)&A[(size_t)rr * HID + c0 + 4];
            uint4 o;
            o.x = (unsigned int)f2bf(f0.x) | ((unsigned int)f2bf(f0.y) << 16);
            o.y = (unsigned int)f2bf(f0.z) | ((unsigned int)f2bf(f0.w) << 16);
            o.z = (unsigned int)f2bf(f1.x) | ((unsigned int)f2bf(f1.y) << 16);
            o.w = (unsigned int)f2bf(f1.z) | ((unsigned int)f2bf(f1.w) << 16);
            *(uint4*)&alds[r * VST + c0] = o;
        }
        __syncthreads();
        #pragma unroll
        for (int kk = 0; kk < 8; kk++){
            short8 bf[2];
            #pragma unroll
            for (int n = 0; n < 2; n++){
                int nt = by * 8 + w * 2 + n;
                bf[n] = bbase[(nt * 8 + kk) * 64 + lid];
            }
            #pragma unroll
            for (int m = 0; m < 4; m++){
                const short8 af = *(const short8*)&alds[(m * 16 + l15) * VST + kk * 32 + quad * 8];
                #pragma unroll
                for (int n = 0; n < 2; n++)
                    acc[m][n] = __builtin_amdgcn_mfma_f32_16x16x32_bf16(af, bf[n], acc[m][n], 0, 0, 0);
            }
        }
    }
    #pragma unroll
    for (int n = 0; n < 2; n++){
        int cg = by * 128 + w * 32 + n * 16 + l15;
        float b = bias ? bias[cg] : 0.f;
        #pragma unroll
        for (int m = 0; m < 4; m++){
            #pragma unroll
            for (int r = 0; r < 4; r++){
                int rg = rb + m * 16 + quad * 4 + r;
                if (rg < NN){
                    float v = acc[m][n][r] + b;
                    if (act) v = silu_f(v);
                    if (R) v += R[(size_t)rg * HID + cg];
                    size_t idx = (size_t)rg * HID + cg;
                    if (obf) ((unsigned short*)C)[idx] = f2bf(v);
                    else     ((float*)C)[idx] = v;
                }
            }
        }
    }
}

// ---- MFMA edge kernel (GCL): 64 perm-ordered edges per block --------------
__global__ __launch_bounds__(256, 4) void k_edge_mfma(
        const unsigned short* __restrict__ HrowB, const unsigned short* __restrict__ HcolB,
        const int* __restrict__ row, const int* __restrict__ col,
        const float* __restrict__ ea, const int* __restrict__ perm,
        const unsigned short* __restrict__ w2f,
        const float* __restrict__ w512, const float* __restrict__ w513,
        const float* __restrict__ eb2, const float* __restrict__ aw, const float* __restrict__ ab,
        float* __restrict__ agg){
    __shared__ unsigned short vlds[MB * VST];
    __shared__ float attp[4][MB];
    __shared__ float attf[MB];
    __shared__ int   nrows[MB];
    __shared__ int   cids[MB];
    __shared__ float ea0s[MB], ea1s[MB];

    int tid = threadIdx.x;
    int e0  = blockIdx.x * MB;
    if (tid < MB){
        int eid = perm[e0 + tid];
        nrows[tid] = row[eid];
        cids[tid]  = col[eid];
        ea0s[tid]  = ea[eid * 2 + 0];
        ea1s[tid]  = ea[eid * 2 + 1];
    }
    __syncthreads();
    {   // staging: 8 rows/iter, 32 thr/row, 8 bf16 cols/thread (16B loads)
        int sr = tid >> 5;
        int c0 = (tid & 31) * 8;
        float4 wa = *(const float4*)&w512[c0];
        float4 wb = *(const float4*)&w512[c0 + 4];
        float4 ua = *(const float4*)&w513[c0];
        float4 ub = *(const float4*)&w513[c0 + 4];
        float w5[8] = {wa.x, wa.y, wa.z, wa.w, wb.x, wb.y, wb.z, wb.w};
        float w6[8] = {ua.x, ua.y, ua.z, ua.w, ub.x, ub.y, ub.z, ub.w};
        for (int it = 0; it < MB / 8; it++){
            int r = it * 8 + sr;
            int nid = nrows[r], cid = cids[r];
            float e0v = ea0s[r], e1v = ea1s[r];
            uint4 hr = *(const uint4*)&HrowB[(size_t)nid * HID + c0];
            uint4 hc = *(const uint4*)&HcolB[(size_t)cid * HID + c0];
            const unsigned int* hru = (const unsigned int*)&hr;
            const unsigned int* hcu = (const unsigned int*)&hc;
            uint4 o;
            unsigned int* op = (unsigned int*)&o;
            #pragma unroll
            for (int q = 0; q < 4; q++){
                float rl = __uint_as_float(hru[q] << 16);
                float rh = __uint_as_float(hru[q] & 0xFFFF0000u);
                float cl = __uint_as_float(hcu[q] << 16);
                float ch = __uint_as_float(hcu[q] & 0xFFFF0000u);
                float v0 = silu_f(rl + cl + e0v * w5[2 * q]     + e1v * w6[2 * q]);
                float v1 = silu_f(rh + ch + e0v * w5[2 * q + 1] + e1v * w6[2 * q + 1]);
                op[q] = (unsigned int)f2bf(v0) | ((unsigned int)f2bf(v1) << 16);
            }
            *(uint4*)&vlds[r * VST + c0] = o;
        }
    }
    __syncthreads();

    int lid = tid & 63, w = tid >> 6;
    int quad = lid >> 4, l15 = lid & 15;

    f32x4 acc[4][4];
    #pragma unroll
    for (int m = 0; m < 4; m++)
        #pragma unroll
        for (int n = 0; n < 4; n++){ f32x4 z = {0.f, 0.f, 0.f, 0.f}; acc[m][n] = z; }

    const short8* bbase = (const short8*)w2f;
    #pragma unroll
    for (int kk = 0; kk < 8; kk++){
        short8 bf[4];
        #pragma unroll
        for (int n = 0; n < 4; n++)
            bf[n] = bbase[((w * 4 + n) * 8 + kk) * 64 + lid];
        #pragma unroll
        for (int m = 0; m < 4; m++){
            const short8 af = *(const short8*)&vlds[(m * 16 + l15) * VST + kk * 32 + quad * 8];
            #pragma unroll
            for (int n = 0; n < 4; n++)
                acc[m][n] = __builtin_amdgcn_mfma_f32_16x16x32_bf16(af, bf[n], acc[m][n], 0, 0, 0);
        }
    }

    // epilogue: mij = silu(acc+eb2); attention row-dot partials
    float b2v[4], awv[4];
    #pragma unroll
    for (int n = 0; n < 4; n++){
        int cg = w * 64 + n * 16 + l15;
        b2v[n] = eb2[cg]; awv[n] = aw[cg];
    }
    #pragma unroll
    for (int m = 0; m < 4; m++){
        float p[4] = {0.f, 0.f, 0.f, 0.f};
        #pragma unroll
        for (int n = 0; n < 4; n++){
            #pragma unroll
            for (int r = 0; r < 4; r++){
                float mij = silu_f(acc[m][n][r] + b2v[n]);
                acc[m][n][r] = mij;
                p[r] += mij * awv[n];
            }
        }
        #pragma unroll
        for (int r = 0; r < 4; r++){
            p[r] += __shfl_xor(p[r], 1);
            p[r] += __shfl_xor(p[r], 2);
            p[r] += __shfl_xor(p[r], 4);
            p[r] += __shfl_xor(p[r], 8);
        }
        if (l15 == 0){
            #pragma unroll
            for (int r = 0; r < 4; r++)
                attp[w][m * 16 + quad * 4 + r] = p[r];
        }
    }
    __syncthreads();
    if (tid < MB){
        float a0 = attp[0][tid] + attp[1][tid] + attp[2][tid] + attp[3][tid] + ab[0];
        attf[tid] = 0.01f * sigm_f(a0);     // fold /NORM_FACTOR into att
    }
    __syncthreads();

    // segment-sum agg via per-segment reduced atomics (rows are CSR-sorted)
    for (int m = 0; m < 4; m++){
        int mb = m * 16;
        float av[4]; int nv[4];
        #pragma unroll
        for (int r = 0; r < 4; r++){
            av[r] = attf[mb + quad * 4 + r];
            nv[r] = nrows[mb + quad * 4 + r];
        }
        float ef[4][4];
        #pragma unroll
        for (int n = 0; n < 4; n++)
            #pragma unroll
            for (int r = 0; r < 4; r++)
                ef[n][r] = acc[m][n][r] * av[r];

        int myn = nrows[mb + l15];
        int t16 = 0;
        while (t16 < 16){
            int tgt = nrows[mb + t16];
            unsigned long long bal = __ballot((lid < 16) && (lid > t16) && (myn != tgt));
            int nxt = bal ? (__ffsll((unsigned long long)bal) - 1) : 16;
            bool whole = (t16 == 0) && (nxt == 16);
            #pragma unroll
            for (int n = 0; n < 4; n++){
                float s = 0.f;
                #pragma unroll
                for (int r = 0; r < 4; r++)
                    s += (whole || nv[r] == tgt) ? ef[n][r] : 0.f;
                s += __shfl_xor(s, 16);
                s += __shfl_xor(s, 32);
                if (lid < 16)
                    atomicAdd(&agg[(size_t)tgt * HID + w * 64 + n * 16 + lid], s);
            }
            t16 = nxt;
        }
    }
}

// ---- MFMA coord kernel: same GEMM, epilogue -> per-edge phi ---------------
__global__ __launch_bounds__(256, 4) void k_coord_mfma(
        const unsigned short* __restrict__ CrowB, const unsigned short* __restrict__ CcolB,
        const int* __restrict__ row, const int* __restrict__ col,
        const float* __restrict__ ea, const int* __restrict__ perm,
        const unsigned short* __restrict__ w2f,
        const float* __restrict__ w512, const float* __restrict__ w513,
        const float* __restrict__ cb2, const float* __restrict__ cw3,
        float* __restrict__ phi){
    __shared__ unsigned short vlds[MB * VST];
    __shared__ float pp[4][MB];
    __shared__ int   nrows[MB];
    __shared__ int   cids[MB];
    __shared__ float ea0s[MB], ea1s[MB];

    int tid = threadIdx.x;
    int e0  = blockIdx.x * MB;
    if (tid < MB){
        int eid = perm[e0 + tid];
        nrows[tid] = row[eid];
        cids[tid]  = col[eid];
        ea0s[tid]  = ea[eid * 2 + 0];
        ea1s[tid]  = ea[eid * 2 + 1];
    }
    __syncthreads();
    {
        int sr = tid >> 5;
        int c0 = (tid & 31) * 8;
        float4 wa = *(const float4*)&w512[c0];
        float4 wb = *(const float4*)&w512[c0 + 4];
        float4 ua = *(const float4*)&w513[c0];
        float4 ub = *(const float4*)&w513[c0 + 4];
        float w5[8] = {wa.x, wa.y, wa.z, wa.w, wb.x, wb.y, wb.z, wb.w};
        float w6[8] = {ua.x, ua.y, ua.z, ua.w, ub.x, ub.y, ub.z, ub.w};
        for (int it = 0; it < MB / 8; it++){
            int r = it * 8 + sr;
            int nid = nrows[r], cid = cids[r];
            float e0v = ea0s[r], e1v = ea1s[r];
            uint4 hr = *(const uint4*)&CrowB[(size_t)nid * HID + c0];
            uint4 hc = *(const uint4*)&CcolB[(size_t)cid * HID + c0];
            const unsigned int* hru = (const unsigned int*)&hr;
            const unsigned int* hcu = (const unsigned int*)&hc;
            uint4 o;
            unsigned int* op = (unsigned int*)&o;
            #pragma unroll
            for (int q = 0; q < 4; q++){
                float rl = __uint_as_float(hru[q] << 16);
                float rh = __uint_as_float(hru[q] & 0xFFFF0000u);
                float cl = __uint_as_float(hcu[q] << 16);
                float ch = __uint_as_float(hcu[q] & 0xFFFF0000u);
                float v0 = silu_f(rl + cl + e0v * w5[2 * q]     + e1v * w6[2 * q]);
                float v1 = silu_f(rh + ch + e0v * w5[2 * q + 1] + e1v * w6[2 * q + 1]);
                op[q] = (unsigned int)f2bf(v0) | ((unsigned int)f2bf(v1) << 16);
            }
            *(uint4*)&vlds[r * VST + c0] = o;
        }
    }
    __syncthreads();

    int lid = tid & 63, w = tid >> 6;
    int quad = lid >> 4, l15 = lid & 15;

    f32x4 acc[4][4];
    #pragma unroll
    for (int m = 0; m < 4; m++)
        #pragma unroll
        for (int n = 0; n < 4; n++){ f32x4 z = {0.f, 0.f, 0.f, 0.f}; acc[m][n] = z; }

    const short8* bbase = (const short8*)w2f;
    #pragma unroll
    for (int kk = 0; kk < 8; kk++){
        short8 bf[4];
        #pragma unroll
        for (int n = 0; n < 4; n++)
            bf[n] = bbase[((w * 4 + n) * 8 + kk) * 64 + lid];
        #pragma unroll
        for (int m = 0; m < 4; m++){
            const short8 af = *(const short8*)&vlds[(m * 16 + l15) * VST + kk * 32 + quad * 8];
            #pragma unroll
            for (int n = 0; n < 4; n++)
                acc[m][n] = __builtin_amdgcn_mfma_f32_16x16x32_bf16(af, bf[n], acc[m][n], 0, 0, 0);
        }
    }

    float b2v[4], w3v[4];
    #pragma unroll
    for (int n = 0; n < 4; n++){
        int cg = w * 64 + n * 16 + l15;
        b2v[n] = cb2[cg]; w3v[n] = cw3[cg];
    }
    #pragma unroll
    for (int m = 0; m < 4; m++){
        float p[4] = {0.f, 0.f, 0.f, 0.f};
        #pragma unroll
        for (int n = 0; n < 4; n++)
            #pragma unroll
            for (int r = 0; r < 4; r++)
                p[r] += silu_f(acc[m][n][r] + b2v[n]) * w3v[n];
        #pragma unroll
        for (int r = 0; r < 4; r++){
            p[r] += __shfl_xor(p[r], 1);
            p[r] += __shfl_xor(p[r], 2);
            p[r] += __shfl_xor(p[r], 4);
            p[r] += __shfl_xor(p[r], 8);
        }
        if (l15 == 0){
            #pragma unroll
            for (int r = 0; r < 4; r++)
                pp[w][m * 16 + quad * 4 + r] = p[r];
        }
    }
    __syncthreads();
    if (tid < MB)
        phi[e0 + tid] = pp[0][tid] + pp[1][tid] + pp[2][tid] + pp[3][tid];
}

// ---- coordinate segment-sum: one wave per node ----------------------------
__global__ __launch_bounds__(64) void k_xupd(const float* __restrict__ x, const float* __restrict__ phi,
                                             const int* __restrict__ col, const int* __restrict__ perm,
                                             const int* __restrict__ rs, float* __restrict__ xout){
    int n = blockIdx.x, lid = threadIdx.x;
    int s = rs[n], e = rs[n + 1];
    float x0 = x[n * 3 + 0], x1 = x[n * 3 + 1], x2 = x[n * 3 + 2];
    float tx = 0.f, ty = 0.f, tz = 0.f;
    for (int i = s + lid; i < e; i += 64){
        int eid = perm[i];
        int c = col[eid];
        float d0 = x0 - x[c * 3 + 0];
        float d1 = x1 - x[c * 3 + 1];
        float d2 = x2 - x[c * 3 + 2];
        float r2 = d0 * d0 + d1 * d1 + d2 * d2;
        float f  = phi[i] / (sqrtf(r2 + 1e-8f) + 1.f);   // NORM_CONST = 1
        tx += d0 * f; ty += d1 * f; tz += d2 * f;
    }
    for (int o = 32; o; o >>= 1){
        tx += __shfl_down(tx, o);
        ty += __shfl_down(ty, o);
        tz += __shfl_down(tz, o);
    }
    if (lid == 0){
        xout[n * 3 + 0] = x0 + 0.01f * tx;
        xout[n * 3 + 1] = x1 + 0.01f * ty;
        xout[n * 3 + 2] = x2 + 0.01f * tz;
    }
}

// ---------------------------------------------------------------------------
extern "C" void kernel_launch(void* const* d_in, const int* in_sizes, int n_in,
                              void* d_out, int out_size, void* d_ws, size_t ws_size,
                              hipStream_t stream){
    const float* h  = (const float*)d_in[0];
    const float* x  = (const float*)d_in[1];
    const int*   ei = (const int*)d_in[2];
    const float* ea = (const float*)d_in[3];
    const int* rowp = ei;
    const int* colp = ei + NE;

    const float* ew1[2] = {(const float*)d_in[4],  (const float*)d_in[14]};
    const float* eb1[2] = {(const float*)d_in[5],  (const float*)d_in[15]};
    const float* ew2[2] = {(const float*)d_in[6],  (const float*)d_in[16]};
    const float* eb2[2] = {(const float*)d_in[7],  (const float*)d_in[17]};
    const float* nw1[2] = {(const float*)d_in[8],  (const float*)d_in[18]};
    const float* nb1[2] = {(const float*)d_in[9],  (const float*)d_in[19]};
    const float* nw2[2] = {(const float*)d_in[10], (const float*)d_in[20]};
    const float* nb2[2] = {(const float*)d_in[11], (const float*)d_in[21]};
    const float* aw[2]  = {(const float*)d_in[12], (const float*)d_in[22]};
    const float* ab[2]  = {(const float*)d_in[13], (const float*)d_in[23]};
    const float* cw1 = (const float*)d_in[24];
    const float* cb1 = (const float*)d_in[25];
    const float* cw2 = (const float*)d_in[26];
    const float* cb2 = (const float*)d_in[27];
    const float* cw3 = (const float*)d_in[28];

    char* w = (char*)d_ws;
    auto alloc = [&](size_t bytes){ void* p = (void*)w; w += (bytes + 255) & ~((size_t)255); return p; };
    int* rs    = (int*)alloc((NN + 1) * sizeof(int));
    int* cur   = (int*)alloc(NN * sizeof(int));
    int* perm  = (int*)alloc(NE * sizeof(int));
    unsigned short* HrowB = (unsigned short*)alloc((size_t)NN * HID * sizeof(unsigned short));
    unsigned short* HcolB = (unsigned short*)alloc((size_t)NN * HID * sizeof(unsigned short));
    float* aggb = (float*)alloc((size_t)NN * HID * sizeof(float));
    unsigned short* wfrag = (unsigned short*)alloc((size_t)15 * HID * HID * sizeof(unsigned short));
    float* phi  = (float*)alloc((size_t)NE * sizeof(float));
    float* Tb   = (float*)HrowB;   // HrowB+HcolB contiguous 10.24 MB, dead when Tb live

    float* hout = (float*)d_out;            // [NN,HID]
    float* xout = hout + (size_t)NN * HID;  // [NN,3]

    // CSR build + weight conversion
    hipMemsetAsync(cur, 0, NN * sizeof(int), stream);
    k_count<<<(NE + 255) / 256, 256, 0, stream>>>(rowp, cur);
    k_scan<<<1, 256, 0, stream>>>(cur, rs, cur);
    k_fill<<<(NE + 255) / 256, 256, 0, stream>>>(rowp, cur, perm);

    CvtPtrs cp;
    for (int l = 0; l < 2; l++){
        cp.p[l * 5 + 0] = ew1[l];
        cp.p[l * 5 + 1] = ew1[l] + 256 * HID;
        cp.p[l * 5 + 2] = nw1[l];
        cp.p[l * 5 + 3] = nw1[l] + 256 * HID;
        cp.p[l * 5 + 4] = nw2[l];
    }
    cp.p[10] = cw1;
    cp.p[11] = cw1 + 256 * HID;
    cp.p[12] = ew2[0];
    cp.p[13] = ew2[1];
    cp.p[14] = cw2;
    k_cvtw<<<15 * 256, 256, 0, stream>>>(cp, wfrag);

    dim3 ggrid(157, 2);
    const float* hcur = h;
    for (int l = 0; l < 2; l++){
        k_dgemm<<<ggrid, 256, 0, stream>>>(hcur, nullptr, wfrag, l * 5 + 0, 0, eb1[l], nullptr, HrowB, 0, 1);
        k_dgemm<<<ggrid, 256, 0, stream>>>(hcur, nullptr, wfrag, l * 5 + 1, 0, nullptr, nullptr, HcolB, 0, 1);
        hipMemsetAsync(aggb, 0, (size_t)NN * HID * sizeof(float), stream);
        k_edge_mfma<<<NEB, 256, 0, stream>>>(HrowB, HcolB, rowp, colp, ea, perm,
                                             wfrag + (size_t)(12 + l) * HID * HID,
                                             ew1[l] + 512 * HID, ew1[l] + 513 * HID,
                                             eb2[l], aw[l], ab[l], aggb);
        k_dgemm<<<ggrid, 256, 0, stream>>>(hcur, aggb, wfrag, l * 5 + 2, l * 5 + 3, nb1[l], nullptr, Tb, 1, 0);
        k_dgemm<<<ggrid, 256, 0, stream>>>(Tb, nullptr, wfrag, l * 5 + 4, 0, nb2[l], hcur, hout, 0, 0);
        hcur = hout;
    }
    // coord update
    k_dgemm<<<ggrid, 256, 0, stream>>>(hout, nullptr, wfrag, 10, 0, cb1, nullptr, HrowB, 0, 1);
    k_dgemm<<<ggrid, 256, 0, stream>>>(hout, nullptr, wfrag, 11, 0, nullptr, nullptr, HcolB, 0, 1);
    k_coord_mfma<<<NEB, 256, 0, stream>>>(HrowB, HcolB, rowp, colp, ea, perm,
                                          wfrag + (size_t)14 * HID * HID,
                                          cw1 + 512 * HID, cw1 + 513 * HID,
                                          cb2, cw3, phi);
    k_xupd<<<NN, 64, 0, stream>>>(x, phi, colp, perm, rs, xout);
}

// Round 4
// 609.905 us; speedup vs baseline: 6.8507x; 1.1968x over previous
//
#include <hip/hip_runtime.h>
#include <hip/hip_fp16.h>
#include <stdint.h>

#define NN   10000
#define NE   320000
#define HID  256
#define MB   64                  // edges per block in MFMA edge kernels
#define NEB  (NE/MB)             // 5000 blocks (exact)
#define VST  264                 // LDS row stride in fp16 elems (528 B)

#define DG_PLAIN 0
#define DG_SPLIT 1
#define DG_2A    2

typedef __attribute__((ext_vector_type(8))) short short8;
typedef __attribute__((ext_vector_type(4))) float f32x4;

struct CvtPtrs { const float* p[15]; };

__device__ __forceinline__ float silu_f(float v){ return v / (1.f + __expf(-v)); }
__device__ __forceinline__ float sigm_f(float v){ return 1.f / (1.f + __expf(-v)); }
__device__ __forceinline__ __half2 silu2(__half2 x){
    __half2 e = h2exp2(__hmul2(x, __float2half2_rn(-1.442695041f)));
    __half2 d = __hadd2(e, __float2half2_rn(1.0f));
    return __hmul2(x, h2rcp(d));
}

// ---- CSR build -------------------------------------------------------------
__global__ __launch_bounds__(256) void k_count(const int* __restrict__ row, int* __restrict__ cnt){
    int e = blockIdx.x * 256 + threadIdx.x;
    if (e < NE) atomicAdd(&cnt[row[e]], 1);
}

__global__ __launch_bounds__(256) void k_scan(const int* __restrict__ cnt, int* __restrict__ rs, int* __restrict__ cur){
    __shared__ int sums[256];
    const int PER = 40;
    int t = threadIdx.x;
    int base = t * PER;
    int s = 0;
    for (int i = 0; i < PER; i++){
        int idx = base + i;
        s += (idx < NN) ? cnt[idx] : 0;
    }
    sums[t] = s;
    __syncthreads();
    for (int off = 1; off < 256; off <<= 1){
        int v = (t >= off) ? sums[t - off] : 0;
        __syncthreads();
        sums[t] += v;
        __syncthreads();
    }
    int run = (t == 0) ? 0 : sums[t - 1];
    for (int i = 0; i < PER; i++){
        int idx = base + i;
        if (idx < NN){
            int c = cnt[idx];
            rs[idx] = run;
            cur[idx] = run;
            run += c;
        }
    }
    if (t == 255) rs[NN] = sums[255];
}

__global__ __launch_bounds__(256) void k_fill(const int* __restrict__ row, int* __restrict__ cur, int* __restrict__ perm){
    int e = blockIdx.x * 256 + threadIdx.x;
    if (e < NE){
        int p = atomicAdd(&cur[row[e]], 1);
        perm[p] = e;
    }
}

// ---- convert 15 [256,256] weight chunks -> fp16, MFMA-B-fragment order ----
// dst idx (within matrix) = ((nt*8 + kk)*64 + lane)*8 + j
// value = W[k][n], k = kk*32+(lane>>4)*8+j, n = nt*16+(lane&15)
__global__ __launch_bounds__(256) void k_cvtw(CvtPtrs pp, __half* __restrict__ dst){
    int i = blockIdx.x * 256 + threadIdx.x;          // [0, 15*65536)
    const float* src = pp.p[i >> 16];
    int t = i & 65535;
    int j = t & 7, lane = (t >> 3) & 63, kk = (t >> 9) & 7, nt = t >> 12;
    int k = kk * 32 + (lane >> 4) * 8 + j;
    int n = nt * 16 + (lane & 15);
    dst[i] = __float2half_rn(src[k * HID + n]);
}

// ---- h fp32 -> fp16 mirror ------------------------------------------------
__global__ __launch_bounds__(256) void k_cvt16(const float* __restrict__ src, __half* __restrict__ dst){
    int i = (blockIdx.x * 256 + threadIdx.x) * 8;    // NN*HID = 2.56M, grid 1250
    float4 f0 = *(const float4*)&src[i];
    float4 f1 = *(const float4*)&src[i + 4];
    uint4 o; __half2* op = (__half2*)&o;
    op[0] = __float22half2_rn(make_float2(f0.x, f0.y));
    op[1] = __float22half2_rn(make_float2(f0.z, f0.w));
    op[2] = __float22half2_rn(make_float2(f1.x, f1.y));
    op[3] = __float22half2_rn(make_float2(f1.z, f1.w));
    *(uint4*)&dst[i] = o;
}

// ---- MFMA dense GEMM ------------------------------------------------------
// modes: PLAIN: out = [R +] act(A1@WA + bias), out32 and/or out16
//        SPLIT: grid.y=4, cols<256 -> out16 (+bias), cols>=256 -> outB16
//        2A   : out = act(A1@WA + A2f@WB + bias)  (A1 fp16, A2f fp32)
__global__ __launch_bounds__(256, 4) void k_dgemm(
        const __half* __restrict__ A1, const float* __restrict__ A2f,
        const __half* __restrict__ wpool, int wAidx, int wBidx,
        const float* __restrict__ bias, const float* __restrict__ R,
        float* __restrict__ out32, __half* __restrict__ out16,
        __half* __restrict__ outB16, int mode, int act){
    __shared__ __half alds[64 * VST];
    int tid = threadIdx.x;
    int lid = tid & 63, w = tid >> 6;
    int quad = lid >> 4, l15 = lid & 15;
    int rb = blockIdx.x * 64;
    int by = blockIdx.y;

    float bv[2]; int cg0[2];
    #pragma unroll
    for (int n = 0; n < 2; n++){
        int cg = by * 128 + w * 32 + n * 16 + l15;
        cg0[n] = cg;
        bv[n] = (bias && cg < 256) ? bias[cg] : 0.f;
    }
    f32x4 acc[4][2];
    #pragma unroll
    for (int m = 0; m < 4; m++)
        #pragma unroll
        for (int n = 0; n < 2; n++){ f32x4 z = {bv[n], bv[n], bv[n], bv[n]}; acc[m][n] = z; }

    int npass = (mode == DG_2A) ? 2 : 1;
    int sr = tid >> 5, c0 = (tid & 31) * 8;
    for (int pass = 0; pass < npass; pass++){
        if (pass) __syncthreads();
        int widx, byl = by;
        if (mode == DG_SPLIT){ if (by >= 2){ widx = wBidx; byl = by - 2; } else widx = wAidx; }
        else widx = pass ? wBidx : wAidx;
        const short8* bbase = (const short8*)(wpool + (size_t)widx * 65536);

        if (pass == 0){
            #pragma unroll
            for (int it = 0; it < 8; it++){
                int r = it * 8 + sr;
                int rr = rb + r; if (rr > NN - 1) rr = NN - 1;
                *(uint4*)&alds[r * VST + c0] = *(const uint4*)&A1[(size_t)rr * HID + c0];
            }
        } else {
            #pragma unroll
            for (int it = 0; it < 8; it++){
                int r = it * 8 + sr;
                int rr = rb + r; if (rr > NN - 1) rr = NN - 1;
                float4 f0 = *(const float4*)&A2f[(size_t)rr * HID + c0];
                float4 f1 = *(const float4*)&A2f[(size_t)rr * HID + c0 + 4];
                uint4 o; __half2* op = (__half2*)&o;
                op[0] = __float22half2_rn(make_float2(f0.x, f0.y));
                op[1] = __float22half2_rn(make_float2(f0.z, f0.w));
                op[2] = __float22half2_rn(make_float2(f1.x, f1.y));
                op[3] = __float22half2_rn(make_float2(f1.z, f1.w));
                *(uint4*)&alds[r * VST + c0] = o;
            }
        }
        __syncthreads();
        #pragma unroll
        for (int kk = 0; kk < 8; kk++){
            short8 bf[2];
            #pragma unroll
            for (int n = 0; n < 2; n++)
                bf[n] = bbase[((byl * 8 + w * 2 + n) * 8 + kk) * 64 + lid];
            #pragma unroll
            for (int m = 0; m < 4; m++){
                const short8 af = *(const short8*)&alds[(m * 16 + l15) * VST + kk * 32 + quad * 8];
                #pragma unroll
                for (int n = 0; n < 2; n++)
                    acc[m][n] = __builtin_amdgcn_mfma_f32_16x16x32_f16(af, bf[n], acc[m][n], 0, 0, 0);
            }
        }
    }
    #pragma unroll
    for (int n = 0; n < 2; n++){
        int cg = cg0[n];
        #pragma unroll
        for (int m = 0; m < 4; m++){
            #pragma unroll
            for (int r = 0; r < 4; r++){
                int rg = rb + m * 16 + quad * 4 + r;
                if (rg < NN){
                    float v = acc[m][n][r];
                    if (act) v = silu_f(v);
                    if (R) v += R[(size_t)rg * HID + cg];
                    if (mode == DG_SPLIT){
                        if (cg < 256) out16[(size_t)rg * HID + cg] = __float2half_rn(v);
                        else          outB16[(size_t)rg * HID + cg - 256] = __float2half_rn(v);
                    } else {
                        if (out32) out32[(size_t)rg * HID + cg] = v;
                        if (out16) out16[(size_t)rg * HID + cg] = __float2half_rn(v);
                    }
                }
            }
        }
    }
}

// ---- MFMA edge kernel (GCL): 64 perm-ordered edges per block --------------
__global__ __launch_bounds__(256, 4) void k_edge_mfma(
        const __half* __restrict__ HrowB, const __half* __restrict__ HcolB,
        const int* __restrict__ row, const int* __restrict__ col,
        const float* __restrict__ ea, const int* __restrict__ perm,
        const __half* __restrict__ w2f,
        const float* __restrict__ w512, const float* __restrict__ w513,
        const float* __restrict__ eb2, const float* __restrict__ aw, const float* __restrict__ ab,
        float* __restrict__ agg){
    __shared__ __half vlds[MB * VST];
    __shared__ float attp[4][MB];
    __shared__ float attf[MB];
    __shared__ int   nrows[MB];
    __shared__ int   cids[MB];
    __shared__ float ea0s[MB], ea1s[MB];

    int tid = threadIdx.x;
    int e0  = blockIdx.x * MB;
    if (tid < MB){
        int eid = perm[e0 + tid];
        nrows[tid] = row[eid];
        cids[tid]  = col[eid];
        ea0s[tid]  = ea[eid * 2 + 0];
        ea1s[tid]  = ea[eid * 2 + 1];
    }
    __syncthreads();
    {   // staging: 8 rows/iter, 32 thr/row, 8 fp16 cols/thread, packed math
        int sr = tid >> 5;
        int c0 = (tid & 31) * 8;
        float4 wa = *(const float4*)&w512[c0];
        float4 wb = *(const float4*)&w512[c0 + 4];
        float4 ua = *(const float4*)&w513[c0];
        float4 ub = *(const float4*)&w513[c0 + 4];
        __half2 w5h[4] = {__float22half2_rn(make_float2(wa.x, wa.y)), __float22half2_rn(make_float2(wa.z, wa.w)),
                          __float22half2_rn(make_float2(wb.x, wb.y)), __float22half2_rn(make_float2(wb.z, wb.w))};
        __half2 w6h[4] = {__float22half2_rn(make_float2(ua.x, ua.y)), __float22half2_rn(make_float2(ua.z, ua.w)),
                          __float22half2_rn(make_float2(ub.x, ub.y)), __float22half2_rn(make_float2(ub.z, ub.w))};
        #pragma unroll
        for (int it = 0; it < 8; it++){
            int r = it * 8 + sr;
            int nid = nrows[r], cid = cids[r];
            __half2 e0h = __float2half2_rn(ea0s[r]);
            __half2 e1h = __float2half2_rn(ea1s[r]);
            uint4 hr4 = *(const uint4*)&HrowB[(size_t)nid * HID + c0];
            uint4 hc4 = *(const uint4*)&HcolB[(size_t)cid * HID + c0];
            const __half2* hrp = (const __half2*)&hr4;
            const __half2* hcp = (const __half2*)&hc4;
            uint4 o; __half2* op = (__half2*)&o;
            #pragma unroll
            for (int q = 0; q < 4; q++){
                __half2 t = __hadd2(hrp[q], hcp[q]);
                t = __hfma2(e0h, w5h[q], t);
                t = __hfma2(e1h, w6h[q], t);
                op[q] = silu2(t);
            }
            *(uint4*)&vlds[r * VST + c0] = o;
        }
    }
    __syncthreads();

    int lid = tid & 63, w = tid >> 6;
    int quad = lid >> 4, l15 = lid & 15;

    float b2v[4], awv[4];
    #pragma unroll
    for (int n = 0; n < 4; n++){
        int cg = w * 64 + n * 16 + l15;
        b2v[n] = eb2[cg]; awv[n] = aw[cg];
    }
    f32x4 acc[4][4];
    #pragma unroll
    for (int m = 0; m < 4; m++)
        #pragma unroll
        for (int n = 0; n < 4; n++){ f32x4 z = {b2v[n], b2v[n], b2v[n], b2v[n]}; acc[m][n] = z; }

    const short8* bbase = (const short8*)w2f;
    #pragma unroll
    for (int kk = 0; kk < 8; kk++){
        short8 bf[4];
        #pragma unroll
        for (int n = 0; n < 4; n++)
            bf[n] = bbase[((w * 4 + n) * 8 + kk) * 64 + lid];
        #pragma unroll
        for (int m = 0; m < 4; m++){
            const short8 af = *(const short8*)&vlds[(m * 16 + l15) * VST + kk * 32 + quad * 8];
            #pragma unroll
            for (int n = 0; n < 4; n++)
                acc[m][n] = __builtin_amdgcn_mfma_f32_16x16x32_f16(af, bf[n], acc[m][n], 0, 0, 0);
        }
    }

    // epilogue: mij = silu(acc); attention row-dot partials
    #pragma unroll
    for (int m = 0; m < 4; m++){
        float p[4] = {0.f, 0.f, 0.f, 0.f};
        #pragma unroll
        for (int n = 0; n < 4; n++){
            #pragma unroll
            for (int r = 0; r < 4; r++){
                float mij = silu_f(acc[m][n][r]);
                acc[m][n][r] = mij;
                p[r] += mij * awv[n];
            }
        }
        #pragma unroll
        for (int r = 0; r < 4; r++){
            p[r] += __shfl_xor(p[r], 1);
            p[r] += __shfl_xor(p[r], 2);
            p[r] += __shfl_xor(p[r], 4);
            p[r] += __shfl_xor(p[r], 8);
        }
        if (l15 == 0){
            #pragma unroll
            for (int r = 0; r < 4; r++)
                attp[w][m * 16 + quad * 4 + r] = p[r];
        }
    }
    __syncthreads();
    if (tid < MB){
        float a0 = attp[0][tid] + attp[1][tid] + attp[2][tid] + attp[3][tid] + ab[0];
        attf[tid] = 0.01f * sigm_f(a0);     // fold /NORM_FACTOR into att
    }
    __syncthreads();

    // segment-sum agg (rows CSR-sorted); fast path: whole 16-tile one segment
    for (int m = 0; m < 4; m++){
        int mb = m * 16;
        float av[4]; int nv[4];
        #pragma unroll
        for (int r = 0; r < 4; r++){
            av[r] = attf[mb + quad * 4 + r];
            nv[r] = nrows[mb + quad * 4 + r];
        }
        int rA = nrows[mb], rB = nrows[mb + 15];
        if (rA == rB){
            #pragma unroll
            for (int n = 0; n < 4; n++){
                float s = acc[m][n][0] * av[0] + acc[m][n][1] * av[1]
                        + acc[m][n][2] * av[2] + acc[m][n][3] * av[3];
                s += __shfl_xor(s, 16);
                s += __shfl_xor(s, 32);
                if (lid < 16)
                    atomicAdd(&agg[(size_t)rA * HID + w * 64 + n * 16 + lid], s);
            }
        } else {
            float ef[4][4];
            #pragma unroll
            for (int n = 0; n < 4; n++)
                #pragma unroll
                for (int r = 0; r < 4; r++)
                    ef[n][r] = acc[m][n][r] * av[r];
            int myn = nrows[mb + l15];
            int t16 = 0;
            while (t16 < 16){
                int tgt = nrows[mb + t16];
                unsigned long long bal = __ballot((lid < 16) && (lid > t16) && (myn != tgt));
                int nxt = bal ? (__ffsll((unsigned long long)bal) - 1) : 16;
                #pragma unroll
                for (int n = 0; n < 4; n++){
                    float s = 0.f;
                    #pragma unroll
                    for (int r = 0; r < 4; r++)
                        s += (nv[r] == tgt) ? ef[n][r] : 0.f;
                    s += __shfl_xor(s, 16);
                    s += __shfl_xor(s, 32);
                    if (lid < 16)
                        atomicAdd(&agg[(size_t)tgt * HID + w * 64 + n * 16 + lid], s);
                }
                t16 = nxt;
            }
        }
    }
}

// ---- MFMA coord kernel: same GEMM, epilogue -> per-edge phi ---------------
__global__ __launch_bounds__(256, 4) void k_coord_mfma(
        const __half* __restrict__ CrowB, const __half* __restrict__ CcolB,
        const int* __restrict__ row, const int* __restrict__ col,
        const float* __restrict__ ea, const int* __restrict__ perm,
        const __half* __restrict__ w2f,
        const float* __restrict__ w512, const float* __restrict__ w513,
        const float* __restrict__ cb2, const float* __restrict__ cw3,
        float* __restrict__ phi){
    __shared__ __half vlds[MB * VST];
    __shared__ float pp[4][MB];
    __shared__ int   nrows[MB];
    __shared__ int   cids[MB];
    __shared__ float ea0s[MB], ea1s[MB];

    int tid = threadIdx.x;
    int e0  = blockIdx.x * MB;
    if (tid < MB){
        int eid = perm[e0 + tid];
        nrows[tid] = row[eid];
        cids[tid]  = col[eid];
        ea0s[tid]  = ea[eid * 2 + 0];
        ea1s[tid]  = ea[eid * 2 + 1];
    }
    __syncthreads();
    {
        int sr = tid >> 5;
        int c0 = (tid & 31) * 8;
        float4 wa = *(const float4*)&w512[c0];
        float4 wb = *(const float4*)&w512[c0 + 4];
        float4 ua = *(const float4*)&w513[c0];
        float4 ub = *(const float4*)&w513[c0 + 4];
        __half2 w5h[4] = {__float22half2_rn(make_float2(wa.x, wa.y)), __float22half2_rn(make_float2(wa.z, wa.w)),
                          __float22half2_rn(make_float2(wb.x, wb.y)), __float22half2_rn(make_float2(wb.z, wb.w))};
        __half2 w6h[4] = {__float22half2_rn(make_float2(ua.x, ua.y)), __float22half2_rn(make_float2(ua.z, ua.w)),
                          __float22half2_rn(make_float2(ub.x, ub.y)), __float22half2_rn(make_float2(ub.z, ub.w))};
        #pragma unroll
        for (int it = 0; it < 8; it++){
            int r = it * 8 + sr;
            int nid = nrows[r], cid = cids[r];
            __half2 e0h = __float2half2_rn(ea0s[r]);
            __half2 e1h = __float2half2_rn(ea1s[r]);
            uint4 hr4 = *(const uint4*)&CrowB[(size_t)nid * HID + c0];
            uint4 hc4 = *(const uint4*)&CcolB[(size_t)cid * HID + c0];
            const __half2* hrp = (const __half2*)&hr4;
            const __half2* hcp = (const __half2*)&hc4;
            uint4 o; __half2* op = (__half2*)&o;
            #pragma unroll
            for (int q = 0; q < 4; q++){
                __half2 t = __hadd2(hrp[q], hcp[q]);
                t = __hfma2(e0h, w5h[q], t);
                t = __hfma2(e1h, w6h[q], t);
                op[q] = silu2(t);
            }
            *(uint4*)&vlds[r * VST + c0] = o;
        }
    }
    __syncthreads();

    int lid = tid & 63, w = tid >> 6;
    int quad = lid >> 4, l15 = lid & 15;

    float b2v[4], w3v[4];
    #pragma unroll
    for (int n = 0; n < 4; n++){
        int cg = w * 64 + n * 16 + l15;
        b2v[n] = cb2[cg]; w3v[n] = cw3[cg];
    }
    f32x4 acc[4][4];
    #pragma unroll
    for (int m = 0; m < 4; m++)
        #pragma unroll
        for (int n = 0; n < 4; n++){ f32x4 z = {b2v[n], b2v[n], b2v[n], b2v[n]}; acc[m][n] = z; }

    const short8* bbase = (const short8*)w2f;
    #pragma unroll
    for (int kk = 0; kk < 8; kk++){
        short8 bf[4];
        #pragma unroll
        for (int n = 0; n < 4; n++)
            bf[n] = bbase[((w * 4 + n) * 8 + kk) * 64 + lid];
        #pragma unroll
        for (int m = 0; m < 4; m++){
            const short8 af = *(const short8*)&vlds[(m * 16 + l15) * VST + kk * 32 + quad * 8];
            #pragma unroll
            for (int n = 0; n < 4; n++)
                acc[m][n] = __builtin_amdgcn_mfma_f32_16x16x32_f16(af, bf[n], acc[m][n], 0, 0, 0);
        }
    }

    #pragma unroll
    for (int m = 0; m < 4; m++){
        float p[4] = {0.f, 0.f, 0.f, 0.f};
        #pragma unroll
        for (int n = 0; n < 4; n++)
            #pragma unroll
            for (int r = 0; r < 4; r++)
                p[r] += silu_f(acc[m][n][r]) * w3v[n];
        #pragma unroll
        for (int r = 0; r < 4; r++){
            p[r] += __shfl_xor(p[r], 1);
            p[r] += __shfl_xor(p[r], 2);
            p[r] += __shfl_xor(p[r], 4);
            p[r] += __shfl_xor(p[r], 8);
        }
        if (l15 == 0){
            #pragma unroll
            for (int r = 0; r < 4; r++)
                pp[w][m * 16 + quad * 4 + r] = p[r];
        }
    }
    __syncthreads();
    if (tid < MB)
        phi[e0 + tid] = pp[0][tid] + pp[1][tid] + pp[2][tid] + pp[3][tid];
}

// ---- coordinate segment-sum: one wave per node ----------------------------
__global__ __launch_bounds__(64) void k_xupd(const float* __restrict__ x, const float* __restrict__ phi,
                                             const int* __restrict__ col, const int* __restrict__ perm,
                                             const int* __restrict__ rs, float* __restrict__ xout){
    int n = blockIdx.x, lid = threadIdx.x;
    int s = rs[n], e = rs[n + 1];
    float x0 = x[n * 3 + 0], x1 = x[n * 3 + 1], x2 = x[n * 3 + 2];
    float tx = 0.f, ty = 0.f, tz = 0.f;
    for (int i = s + lid; i < e; i += 64){
        int eid = perm[i];
        int c = col[eid];
        float d0 = x0 - x[c * 3 + 0];
        float d1 = x1 - x[c * 3 + 1];
        float d2 = x2 - x[c * 3 + 2];
        float r2 = d0 * d0 + d1 * d1 + d2 * d2;
        float f  = phi[i] / (sqrtf(r2 + 1e-8f) + 1.f);   // NORM_CONST = 1
        tx += d0 * f; ty += d1 * f; tz += d2 * f;
    }
    for (int o = 32; o; o >>= 1){
        tx += __shfl_down(tx, o);
        ty += __shfl_down(ty, o);
        tz += __shfl_down(tz, o);
    }
    if (lid == 0){
        xout[n * 3 + 0] = x0 + 0.01f * tx;
        xout[n * 3 + 1] = x1 + 0.01f * ty;
        xout[n * 3 + 2] = x2 + 0.01f * tz;
    }
}

// ---------------------------------------------------------------------------
extern "C" void kernel_launch(void* const* d_in, const int* in_sizes, int n_in,
                              void* d_out, int out_size, void* d_ws, size_t ws_size,
                              hipStream_t stream){
    const float* h  = (const float*)d_in[0];
    const float* x  = (const float*)d_in[1];
    const int*   ei = (const int*)d_in[2];
    const float* ea = (const float*)d_in[3];
    const int* rowp = ei;
    const int* colp = ei + NE;

    const float* ew1[2] = {(const float*)d_in[4],  (const float*)d_in[14]};
    const float* eb1[2] = {(const float*)d_in[5],  (const float*)d_in[15]};
    const float* ew2[2] = {(const float*)d_in[6],  (const float*)d_in[16]};
    const float* eb2[2] = {(const float*)d_in[7],  (const float*)d_in[17]};
    const float* nw1[2] = {(const float*)d_in[8],  (const float*)d_in[18]};
    const float* nb1[2] = {(const float*)d_in[9],  (const float*)d_in[19]};
    const float* nw2[2] = {(const float*)d_in[10], (const float*)d_in[20]};
    const float* nb2[2] = {(const float*)d_in[11], (const float*)d_in[21]};
    const float* aw[2]  = {(const float*)d_in[12], (const float*)d_in[22]};
    const float* ab[2]  = {(const float*)d_in[13], (const float*)d_in[23]};
    const float* cw1 = (const float*)d_in[24];
    const float* cb1 = (const float*)d_in[25];
    const float* cw2 = (const float*)d_in[26];
    const float* cb2 = (const float*)d_in[27];
    const float* cw3 = (const float*)d_in[28];

    char* w = (char*)d_ws;
    auto alloc = [&](size_t bytes){ void* p = (void*)w; w += (bytes + 255) & ~((size_t)255); return p; };
    int* rs    = (int*)alloc((NN + 1) * sizeof(int));
    int* cur   = (int*)alloc(NN * sizeof(int));
    int* perm  = (int*)alloc(NE * sizeof(int));
    __half* HrowB = (__half*)alloc((size_t)NN * HID * sizeof(__half));
    __half* HcolB = (__half*)alloc((size_t)NN * HID * sizeof(__half));
    float*  aggb  = (float*)alloc((size_t)NN * HID * sizeof(float));
    __half* wfrag = (__half*)alloc((size_t)15 * HID * HID * sizeof(__half));
    float*  phi   = (float*)alloc((size_t)NE * sizeof(float));
    __half* h16   = (__half*)alloc((size_t)NN * HID * sizeof(__half));
    __half* Tb16  = HrowB;   // HrowB dead after edge kernel; reuse for node-MLP hidden

    float* hout = (float*)d_out;            // [NN,HID]
    float* xout = hout + (size_t)NN * HID;  // [NN,3]

    // CSR build + conversions
    hipMemsetAsync(cur, 0, NN * sizeof(int), stream);
    k_count<<<(NE + 255) / 256, 256, 0, stream>>>(rowp, cur);
    k_scan<<<1, 256, 0, stream>>>(cur, rs, cur);
    k_fill<<<(NE + 255) / 256, 256, 0, stream>>>(rowp, cur, perm);

    CvtPtrs cp;
    for (int l = 0; l < 2; l++){
        cp.p[l * 5 + 0] = ew1[l];
        cp.p[l * 5 + 1] = ew1[l] + 256 * HID;
        cp.p[l * 5 + 2] = nw1[l];
        cp.p[l * 5 + 3] = nw1[l] + 256 * HID;
        cp.p[l * 5 + 4] = nw2[l];
    }
    cp.p[10] = cw1;
    cp.p[11] = cw1 + 256 * HID;
    cp.p[12] = ew2[0];
    cp.p[13] = ew2[1];
    cp.p[14] = cw2;
    k_cvtw<<<15 * 256, 256, 0, stream>>>(cp, wfrag);
    k_cvt16<<<1250, 256, 0, stream>>>(h, h16);

    dim3 g2(157, 2), g4(157, 4);
    const float* hres = h;
    for (int l = 0; l < 2; l++){
        // [Hrow|Hcol] = h@[ew1a|ew1b] (+eb1 on first half), fp16 outs, one dispatch
        k_dgemm<<<g4, 256, 0, stream>>>(h16, nullptr, wfrag, l * 5 + 0, l * 5 + 1,
                                        eb1[l], nullptr, nullptr, HrowB, HcolB, DG_SPLIT, 0);
        hipMemsetAsync(aggb, 0, (size_t)NN * HID * sizeof(float), stream);
        k_edge_mfma<<<NEB, 256, 0, stream>>>(HrowB, HcolB, rowp, colp, ea, perm,
                                             wfrag + (size_t)(12 + l) * HID * HID,
                                             ew1[l] + 512 * HID, ew1[l] + 513 * HID,
                                             eb2[l], aw[l], ab[l], aggb);
        // T = silu(h@nw1a + agg@nw1b + nb1)  -> fp16
        k_dgemm<<<g2, 256, 0, stream>>>(h16, aggb, wfrag, l * 5 + 2, l * 5 + 3,
                                        nb1[l], nullptr, nullptr, Tb16, nullptr, DG_2A, 1);
        // h = hres + T@nw2 + nb2  -> fp32 (d_out) + fp16 mirror
        k_dgemm<<<g2, 256, 0, stream>>>(Tb16, nullptr, wfrag, l * 5 + 4, 0,
                                        nb2[l], hres, hout, h16, nullptr, DG_PLAIN, 0);
        hres = hout;
    }
    // coord update
    k_dgemm<<<g4, 256, 0, stream>>>(h16, nullptr, wfrag, 10, 11,
                                    cb1, nullptr, nullptr, HrowB, HcolB, DG_SPLIT, 0);
    k_coord_mfma<<<NEB, 256, 0, stream>>>(HrowB, HcolB, rowp, colp, ea, perm,
                                          wfrag + (size_t)14 * HID * HID,
                                          cw1 + 512 * HID, cw1 + 513 * HID,
                                          cb2, cw3, phi);
    k_xupd<<<NN, 64, 0, stream>>>(x, phi, colp, perm, rs, xout);
}

// Round 5
// 561.060 us; speedup vs baseline: 7.4471x; 1.0871x over previous
//
#include <hip/hip_runtime.h>
#include <hip/hip_fp16.h>
#include <stdint.h>

#define NN   10000
#define NE   320000
#define HID  256
#define MB   64                  // edges per block in MFMA edge kernels
#define NEB  (NE/MB)             // 5000 blocks (exact)

#define DG_PLAIN 0
#define DG_SPLIT 1
#define DG_2A    2

typedef __attribute__((ext_vector_type(8))) short short8;
typedef __attribute__((ext_vector_type(4))) float f32x4;

struct CvtPtrs { const float* p[15]; };

__device__ __forceinline__ float silu_f(float v){ return v / (1.f + __expf(-v)); }
__device__ __forceinline__ float sigm_f(float v){ return 1.f / (1.f + __expf(-v)); }
__device__ __forceinline__ __half2 silu2(__half2 x){
    __half2 e = h2exp2(__hmul2(x, __float2half2_rn(-1.442695041f)));
    __half2 d = __hadd2(e, __float2half2_rn(1.0f));
    return __hmul2(x, h2rcp(d));
}
__device__ __forceinline__ __half2 h2shfl_xor_add(__half2 v, int m){
    int pi = *(int*)&v;
    pi = __shfl_xor(pi, m, 64);
    __half2 q = *(__half2*)&pi;
    return __hadd2(v, q);
}

// ---- CSR build -------------------------------------------------------------
__global__ __launch_bounds__(256) void k_count(const int* __restrict__ row, int* __restrict__ cnt){
    int e = blockIdx.x * 256 + threadIdx.x;
    if (e < NE) atomicAdd(&cnt[row[e]], 1);
}

__global__ __launch_bounds__(256) void k_scan(const int* __restrict__ cnt, int* __restrict__ rs, int* __restrict__ cur){
    __shared__ int sums[256];
    const int PER = 40;
    int t = threadIdx.x;
    int base = t * PER;
    int s = 0;
    for (int i = 0; i < PER; i++){
        int idx = base + i;
        s += (idx < NN) ? cnt[idx] : 0;
    }
    sums[t] = s;
    __syncthreads();
    for (int off = 1; off < 256; off <<= 1){
        int v = (t >= off) ? sums[t - off] : 0;
        __syncthreads();
        sums[t] += v;
        __syncthreads();
    }
    int run = (t == 0) ? 0 : sums[t - 1];
    for (int i = 0; i < PER; i++){
        int idx = base + i;
        if (idx < NN){
            int c = cnt[idx];
            rs[idx] = run;
            cur[idx] = run;
            run += c;
        }
    }
    if (t == 255) rs[NN] = sums[255];
}

__global__ __launch_bounds__(256) void k_fill(const int* __restrict__ row, int* __restrict__ cur, int* __restrict__ perm){
    int e = blockIdx.x * 256 + threadIdx.x;
    if (e < NE){
        int p = atomicAdd(&cur[row[e]], 1);
        perm[p] = e;
    }
}

// ---- convert 15 [256,256] weight chunks -> fp16, MFMA-B-fragment order ----
__global__ __launch_bounds__(256) void k_cvtw(CvtPtrs pp, __half* __restrict__ dst){
    int i = blockIdx.x * 256 + threadIdx.x;          // [0, 15*65536)
    const float* src = pp.p[i >> 16];
    int t = i & 65535;
    int j = t & 7, lane = (t >> 3) & 63, kk = (t >> 9) & 7, nt = t >> 12;
    int k = kk * 32 + (lane >> 4) * 8 + j;
    int n = nt * 16 + (lane & 15);
    dst[i] = __float2half_rn(src[k * HID + n]);
}

// ---- h fp32 -> fp16 mirror ------------------------------------------------
__global__ __launch_bounds__(256) void k_cvt16(const float* __restrict__ src, __half* __restrict__ dst){
    int i = (blockIdx.x * 256 + threadIdx.x) * 8;    // NN*HID = 2.56M, grid 1250
    float4 f0 = *(const float4*)&src[i];
    float4 f1 = *(const float4*)&src[i + 4];
    uint4 o; __half2* op = (__half2*)&o;
    op[0] = __float22half2_rn(make_float2(f0.x, f0.y));
    op[1] = __float22half2_rn(make_float2(f0.z, f0.w));
    op[2] = __float22half2_rn(make_float2(f1.x, f1.y));
    op[3] = __float22half2_rn(make_float2(f1.z, f1.w));
    *(uint4*)&dst[i] = o;
}

// ---- MFMA dense GEMM (XOR-swizzled LDS) -----------------------------------
__global__ __launch_bounds__(256, 4) void k_dgemm(
        const __half* __restrict__ A1, const float* __restrict__ A2f,
        const __half* __restrict__ wpool, int wAidx, int wBidx,
        const float* __restrict__ bias, const float* __restrict__ R,
        float* __restrict__ out32, __half* __restrict__ out16,
        __half* __restrict__ outB16, int mode, int act){
    __shared__ __half alds[64 * 256];
    int tid = threadIdx.x;
    int lid = tid & 63, w = tid >> 6;
    int quad = lid >> 4, l15 = lid & 15;
    int rb = blockIdx.x * 64;
    int by = blockIdx.y;
    int xorv = l15 & 7;

    float bv[2]; int cg0[2];
    #pragma unroll
    for (int n = 0; n < 2; n++){
        int cg = by * 128 + w * 32 + n * 16 + l15;
        cg0[n] = cg;
        bv[n] = (bias && cg < 256) ? bias[cg] : 0.f;
    }
    f32x4 acc[4][2];
    #pragma unroll
    for (int m = 0; m < 4; m++)
        #pragma unroll
        for (int n = 0; n < 2; n++){ f32x4 z = {bv[n], bv[n], bv[n], bv[n]}; acc[m][n] = z; }

    int npass = (mode == DG_2A) ? 2 : 1;
    int sr = tid >> 5;
    int c0 = (tid & 31) * 8;                       // logical column
    int pc = (((tid & 31) ^ sr) * 8);              // physical (swizzled) LDS column
    for (int pass = 0; pass < npass; pass++){
        if (pass) __syncthreads();
        int widx, byl = by;
        if (mode == DG_SPLIT){ if (by >= 2){ widx = wBidx; byl = by - 2; } else widx = wAidx; }
        else widx = pass ? wBidx : wAidx;
        const short8* bbase = (const short8*)(wpool + (size_t)widx * 65536);

        if (pass == 0){
            #pragma unroll
            for (int it = 0; it < 8; it++){
                int r = it * 8 + sr;
                int rr = rb + r; if (rr > NN - 1) rr = NN - 1;
                *(uint4*)&alds[r * 256 + pc] = *(const uint4*)&A1[(size_t)rr * HID + c0];
            }
        } else {
            #pragma unroll
            for (int it = 0; it < 8; it++){
                int r = it * 8 + sr;
                int rr = rb + r; if (rr > NN - 1) rr = NN - 1;
                float4 f0 = *(const float4*)&A2f[(size_t)rr * HID + c0];
                float4 f1 = *(const float4*)&A2f[(size_t)rr * HID + c0 + 4];
                uint4 o; __half2* op = (__half2*)&o;
                op[0] = __float22half2_rn(make_float2(f0.x, f0.y));
                op[1] = __float22half2_rn(make_float2(f0.z, f0.w));
                op[2] = __float22half2_rn(make_float2(f1.x, f1.y));
                op[3] = __float22half2_rn(make_float2(f1.z, f1.w));
                *(uint4*)&alds[r * 256 + pc] = o;
            }
        }
        __syncthreads();
        #pragma unroll
        for (int kk = 0; kk < 8; kk++){
            short8 bf[2];
            #pragma unroll
            for (int n = 0; n < 2; n++)
                bf[n] = bbase[((byl * 8 + w * 2 + n) * 8 + kk) * 64 + lid];
            #pragma unroll
            for (int m = 0; m < 4; m++){
                const short8 af = *(const short8*)&alds[(m * 16 + l15) * 256 + (((kk * 4 + quad) ^ xorv) * 8)];
                #pragma unroll
                for (int n = 0; n < 2; n++)
                    acc[m][n] = __builtin_amdgcn_mfma_f32_16x16x32_f16(af, bf[n], acc[m][n], 0, 0, 0);
            }
        }
    }
    #pragma unroll
    for (int n = 0; n < 2; n++){
        int cg = cg0[n];
        #pragma unroll
        for (int m = 0; m < 4; m++){
            #pragma unroll
            for (int r = 0; r < 4; r++){
                int rg = rb + m * 16 + quad * 4 + r;
                if (rg < NN){
                    float v = acc[m][n][r];
                    if (act) v = silu_f(v);
                    if (R) v += R[(size_t)rg * HID + cg];
                    if (mode == DG_SPLIT){
                        if (cg < 256) out16[(size_t)rg * HID + cg] = __float2half_rn(v);
                        else          outB16[(size_t)rg * HID + cg - 256] = __float2half_rn(v);
                    } else {
                        if (out32) out32[(size_t)rg * HID + cg] = v;
                        if (out16) out16[(size_t)rg * HID + cg] = __float2half_rn(v);
                    }
                }
            }
        }
    }
}

// ---- MFMA edge kernel (GCL): 64 perm-ordered edges per block --------------
__global__ __launch_bounds__(256, 4) void k_edge_mfma(
        const __half* __restrict__ HrowB, const __half* __restrict__ HcolB,
        const int* __restrict__ row, const int* __restrict__ col,
        const float* __restrict__ ea, const int* __restrict__ perm,
        const __half* __restrict__ w2f,
        const float* __restrict__ w512, const float* __restrict__ w513,
        const float* __restrict__ eb2, const float* __restrict__ aw, const float* __restrict__ ab,
        float* __restrict__ agg){
    __shared__ __half vlds[MB * 256];
    __shared__ unsigned int attp2[4][MB / 2];
    __shared__ float attf[MB];
    __shared__ int   nrows[MB];
    __shared__ int   cids[MB];
    __shared__ float ea0s[MB], ea1s[MB];

    int tid = threadIdx.x;
    int e0  = blockIdx.x * MB;
    float ab0 = ab[0];
    if (tid < MB){
        int eid = perm[e0 + tid];
        nrows[tid] = row[eid];
        cids[tid]  = col[eid];
        ea0s[tid]  = ea[eid * 2 + 0];
        ea1s[tid]  = ea[eid * 2 + 1];
    }
    __syncthreads();
    {   // staging: 8 rows/iter, 32 thr/row, 8 fp16 cols/thread, packed math
        int sr = tid >> 5;
        int c0 = (tid & 31) * 8;
        int pc = ((tid & 31) ^ sr) * 8;            // swizzled LDS chunk
        float4 wa = *(const float4*)&w512[c0];
        float4 wb = *(const float4*)&w512[c0 + 4];
        float4 ua = *(const float4*)&w513[c0];
        float4 ub = *(const float4*)&w513[c0 + 4];
        __half2 w5h[4] = {__float22half2_rn(make_float2(wa.x, wa.y)), __float22half2_rn(make_float2(wa.z, wa.w)),
                          __float22half2_rn(make_float2(wb.x, wb.y)), __float22half2_rn(make_float2(wb.z, wb.w))};
        __half2 w6h[4] = {__float22half2_rn(make_float2(ua.x, ua.y)), __float22half2_rn(make_float2(ua.z, ua.w)),
                          __float22half2_rn(make_float2(ub.x, ub.y)), __float22half2_rn(make_float2(ub.z, ub.w))};
        #pragma unroll
        for (int it = 0; it < 8; it++){
            int r = it * 8 + sr;
            int nid = nrows[r], cid = cids[r];
            __half2 e0h = __float2half2_rn(ea0s[r]);
            __half2 e1h = __float2half2_rn(ea1s[r]);
            uint4 hr4 = *(const uint4*)&HrowB[(size_t)nid * HID + c0];
            uint4 hc4 = *(const uint4*)&HcolB[(size_t)cid * HID + c0];
            const __half2* hrp = (const __half2*)&hr4;
            const __half2* hcp = (const __half2*)&hc4;
            uint4 o; __half2* op = (__half2*)&o;
            #pragma unroll
            for (int q = 0; q < 4; q++){
                __half2 t = __hadd2(hrp[q], hcp[q]);
                t = __hfma2(e0h, w5h[q], t);
                t = __hfma2(e1h, w6h[q], t);
                op[q] = silu2(t);
            }
            *(uint4*)&vlds[r * 256 + pc] = o;
        }
    }
    __syncthreads();

    int lid = tid & 63, w = tid >> 6;
    int quad = lid >> 4, l15 = lid & 15;
    int xorv = l15 & 7;

    float b2v[4]; __half2 aw2[4];
    #pragma unroll
    for (int n = 0; n < 4; n++){
        int cg = w * 64 + n * 16 + l15;
        b2v[n] = eb2[cg];
        aw2[n] = __float2half2_rn(aw[cg]);
    }
    f32x4 acc[4][4];
    #pragma unroll
    for (int m = 0; m < 4; m++)
        #pragma unroll
        for (int n = 0; n < 4; n++){ f32x4 z = {b2v[n], b2v[n], b2v[n], b2v[n]}; acc[m][n] = z; }

    const short8* bbase = (const short8*)w2f;
    #pragma unroll
    for (int kk = 0; kk < 8; kk++){
        short8 bf[4];
        #pragma unroll
        for (int n = 0; n < 4; n++)
            bf[n] = bbase[((w * 4 + n) * 8 + kk) * 64 + lid];
        #pragma unroll
        for (int m = 0; m < 4; m++){
            const short8 af = *(const short8*)&vlds[(m * 16 + l15) * 256 + (((kk * 4 + quad) ^ xorv) * 8)];
            #pragma unroll
            for (int n = 0; n < 4; n++)
                acc[m][n] = __builtin_amdgcn_mfma_f32_16x16x32_f16(af, bf[n], acc[m][n], 0, 0, 0);
        }
    }

    // packed epilogue: mij = silu2(pack(acc)); attention partials in fp16
    __half2 mijp[4][4][2];          // [m][n][pair]: (r0,r1),(r2,r3)
    #pragma unroll
    for (int m = 0; m < 4; m++){
        __half2 p2a = __float2half2_rn(0.f), p2b = p2a;
        #pragma unroll
        for (int n = 0; n < 4; n++){
            __half2 ha = silu2(__float22half2_rn(make_float2(acc[m][n][0], acc[m][n][1])));
            __half2 hb = silu2(__float22half2_rn(make_float2(acc[m][n][2], acc[m][n][3])));
            mijp[m][n][0] = ha; mijp[m][n][1] = hb;
            p2a = __hfma2(ha, aw2[n], p2a);
            p2b = __hfma2(hb, aw2[n], p2b);
        }
        p2a = h2shfl_xor_add(p2a, 1); p2a = h2shfl_xor_add(p2a, 2);
        p2a = h2shfl_xor_add(p2a, 4); p2a = h2shfl_xor_add(p2a, 8);
        p2b = h2shfl_xor_add(p2b, 1); p2b = h2shfl_xor_add(p2b, 2);
        p2b = h2shfl_xor_add(p2b, 4); p2b = h2shfl_xor_add(p2b, 8);
        if (l15 == 0){
            attp2[w][m * 8 + quad * 2 + 0] = *(unsigned int*)&p2a;
            attp2[w][m * 8 + quad * 2 + 1] = *(unsigned int*)&p2b;
        }
    }
    __syncthreads();
    if (tid < MB){
        int pr = tid >> 1;
        unsigned int u0 = attp2[0][pr], u1 = attp2[1][pr], u2 = attp2[2][pr], u3 = attp2[3][pr];
        __half2 h0 = *(__half2*)&u0, h1 = *(__half2*)&u1, h2 = *(__half2*)&u2, h3 = *(__half2*)&u3;
        float lo = __low2float(h0) + __low2float(h1) + __low2float(h2) + __low2float(h3);
        float hi = __high2float(h0) + __high2float(h1) + __high2float(h2) + __high2float(h3);
        float a0 = ((tid & 1) ? hi : lo) + ab0;
        attf[tid] = 0.01f * sigm_f(a0);     // fold /NORM_FACTOR into att
    }
    __syncthreads();

    // segment-sum agg (rows CSR-sorted); fast path: whole 16-tile one segment
    for (int m = 0; m < 4; m++){
        int mb = m * 16;
        __half2 at2a = __float22half2_rn(make_float2(attf[mb + quad * 4 + 0], attf[mb + quad * 4 + 1]));
        __half2 at2b = __float22half2_rn(make_float2(attf[mb + quad * 4 + 2], attf[mb + quad * 4 + 3]));
        int rA = nrows[mb], rB = nrows[mb + 15];
        if (rA == rB){
            #pragma unroll
            for (int n = 0; n < 4; n++){
                __half2 s2 = __hmul2(mijp[m][n][0], at2a);
                s2 = __hfma2(mijp[m][n][1], at2b, s2);
                float s = __low2float(s2) + __high2float(s2);
                s += __shfl_xor(s, 16);
                s += __shfl_xor(s, 32);
                if (lid < 16)
                    atomicAdd(&agg[(size_t)rA * HID + w * 64 + n * 16 + lid], s);
            }
        } else {
            float ef[4][4]; int nv[4];
            #pragma unroll
            for (int r = 0; r < 4; r++) nv[r] = nrows[mb + quad * 4 + r];
            #pragma unroll
            for (int n = 0; n < 4; n++){
                __half2 ea2 = __hmul2(mijp[m][n][0], at2a);
                __half2 eb2h = __hmul2(mijp[m][n][1], at2b);
                ef[n][0] = __low2float(ea2);  ef[n][1] = __high2float(ea2);
                ef[n][2] = __low2float(eb2h); ef[n][3] = __high2float(eb2h);
            }
            int myn = nrows[mb + l15];
            int t16 = 0;
            while (t16 < 16){
                int tgt = nrows[mb + t16];
                unsigned long long bal = __ballot((lid < 16) && (lid > t16) && (myn != tgt));
                int nxt = bal ? (__ffsll((unsigned long long)bal) - 1) : 16;
                #pragma unroll
                for (int n = 0; n < 4; n++){
                    float s = 0.f;
                    #pragma unroll
                    for (int r = 0; r < 4; r++)
                        s += (nv[r] == tgt) ? ef[n][r] : 0.f;
                    s += __shfl_xor(s, 16);
                    s += __shfl_xor(s, 32);
                    if (lid < 16)
                        atomicAdd(&agg[(size_t)tgt * HID + w * 64 + n * 16 + lid], s);
                }
                t16 = nxt;
            }
        }
    }
}

// ---- MFMA coord kernel: same GEMM, epilogue -> per-edge phi ---------------
__global__ __launch_bounds__(256, 4) void k_coord_mfma(
        const __half* __restrict__ CrowB, const __half* __restrict__ CcolB,
        const int* __restrict__ row, const int* __restrict__ col,
        const float* __restrict__ ea, const int* __restrict__ perm,
        const __half* __restrict__ w2f,
        const float* __restrict__ w512, const float* __restrict__ w513,
        const float* __restrict__ cb2, const float* __restrict__ cw3,
        float* __restrict__ phi){
    __shared__ __half vlds[MB * 256];
    __shared__ unsigned int pp2[4][MB / 2];
    __shared__ int   nrows[MB];
    __shared__ int   cids[MB];
    __shared__ float ea0s[MB], ea1s[MB];

    int tid = threadIdx.x;
    int e0  = blockIdx.x * MB;
    if (tid < MB){
        int eid = perm[e0 + tid];
        nrows[tid] = row[eid];
        cids[tid]  = col[eid];
        ea0s[tid]  = ea[eid * 2 + 0];
        ea1s[tid]  = ea[eid * 2 + 1];
    }
    __syncthreads();
    {
        int sr = tid >> 5;
        int c0 = (tid & 31) * 8;
        int pc = ((tid & 31) ^ sr) * 8;
        float4 wa = *(const float4*)&w512[c0];
        float4 wb = *(const float4*)&w512[c0 + 4];
        float4 ua = *(const float4*)&w513[c0];
        float4 ub = *(const float4*)&w513[c0 + 4];
        __half2 w5h[4] = {__float22half2_rn(make_float2(wa.x, wa.y)), __float22half2_rn(make_float2(wa.z, wa.w)),
                          __float22half2_rn(make_float2(wb.x, wb.y)), __float22half2_rn(make_float2(wb.z, wb.w))};
        __half2 w6h[4] = {__float22half2_rn(make_float2(ua.x, ua.y)), __float22half2_rn(make_float2(ua.z, ua.w)),
                          __float22half2_rn(make_float2(ub.x, ub.y)), __float22half2_rn(make_float2(ub.z, ub.w))};
        #pragma unroll
        for (int it = 0; it < 8; it++){
            int r = it * 8 + sr;
            int nid = nrows[r], cid = cids[r];
            __half2 e0h = __float2half2_rn(ea0s[r]);
            __half2 e1h = __float2half2_rn(ea1s[r]);
            uint4 hr4 = *(const uint4*)&CrowB[(size_t)nid * HID + c0];
            uint4 hc4 = *(const uint4*)&CcolB[(size_t)cid * HID + c0];
            const __half2* hrp = (const __half2*)&hr4;
            const __half2* hcp = (const __half2*)&hc4;
            uint4 o; __half2* op = (__half2*)&o;
            #pragma unroll
            for (int q = 0; q < 4; q++){
                __half2 t = __hadd2(hrp[q], hcp[q]);
                t = __hfma2(e0h, w5h[q], t);
                t = __hfma2(e1h, w6h[q], t);
                op[q] = silu2(t);
            }
            *(uint4*)&vlds[r * 256 + pc] = o;
        }
    }
    __syncthreads();

    int lid = tid & 63, w = tid >> 6;
    int quad = lid >> 4, l15 = lid & 15;
    int xorv = l15 & 7;

    float b2v[4]; __half2 w32[4];
    #pragma unroll
    for (int n = 0; n < 4; n++){
        int cg = w * 64 + n * 16 + l15;
        b2v[n] = cb2[cg];
        w32[n] = __float2half2_rn(cw3[cg]);
    }
    f32x4 acc[4][4];
    #pragma unroll
    for (int m = 0; m < 4; m++)
        #pragma unroll
        for (int n = 0; n < 4; n++){ f32x4 z = {b2v[n], b2v[n], b2v[n], b2v[n]}; acc[m][n] = z; }

    const short8* bbase = (const short8*)w2f;
    #pragma unroll
    for (int kk = 0; kk < 8; kk++){
        short8 bf[4];
        #pragma unroll
        for (int n = 0; n < 4; n++)
            bf[n] = bbase[((w * 4 + n) * 8 + kk) * 64 + lid];
        #pragma unroll
        for (int m = 0; m < 4; m++){
            const short8 af = *(const short8*)&vlds[(m * 16 + l15) * 256 + (((kk * 4 + quad) ^ xorv) * 8)];
            #pragma unroll
            for (int n = 0; n < 4; n++)
                acc[m][n] = __builtin_amdgcn_mfma_f32_16x16x32_f16(af, bf[n], acc[m][n], 0, 0, 0);
        }
    }

    #pragma unroll
    for (int m = 0; m < 4; m++){
        __half2 p2a = __float2half2_rn(0.f), p2b = p2a;
        #pragma unroll
        for (int n = 0; n < 4; n++){
            __half2 ha = silu2(__float22half2_rn(make_float2(acc[m][n][0], acc[m][n][1])));
            __half2 hb = silu2(__float22half2_rn(make_float2(acc[m][n][2], acc[m][n][3])));
            p2a = __hfma2(ha, w32[n], p2a);
            p2b = __hfma2(hb, w32[n], p2b);
        }
        p2a = h2shfl_xor_add(p2a, 1); p2a = h2shfl_xor_add(p2a, 2);
        p2a = h2shfl_xor_add(p2a, 4); p2a = h2shfl_xor_add(p2a, 8);
        p2b = h2shfl_xor_add(p2b, 1); p2b = h2shfl_xor_add(p2b, 2);
        p2b = h2shfl_xor_add(p2b, 4); p2b = h2shfl_xor_add(p2b, 8);
        if (l15 == 0){
            pp2[w][m * 8 + quad * 2 + 0] = *(unsigned int*)&p2a;
            pp2[w][m * 8 + quad * 2 + 1] = *(unsigned int*)&p2b;
        }
    }
    __syncthreads();
    if (tid < MB){
        int pr = tid >> 1;
        unsigned int u0 = pp2[0][pr], u1 = pp2[1][pr], u2 = pp2[2][pr], u3 = pp2[3][pr];
        __half2 h0 = *(__half2*)&u0, h1 = *(__half2*)&u1, h2 = *(__half2*)&u2, h3 = *(__half2*)&u3;
        float lo = __low2float(h0) + __low2float(h1) + __low2float(h2) + __low2float(h3);
        float hi = __high2float(h0) + __high2float(h1) + __high2float(h2) + __high2float(h3);
        phi[e0 + tid] = (tid & 1) ? hi : lo;
    }
}

// ---- coordinate segment-sum: one wave per node ----------------------------
__global__ __launch_bounds__(64) void k_xupd(const float* __restrict__ x, const float* __restrict__ phi,
                                             const int* __restrict__ col, const int* __restrict__ perm,
                                             const int* __restrict__ rs, float* __restrict__ xout){
    int n = blockIdx.x, lid = threadIdx.x;
    int s = rs[n], e = rs[n + 1];
    float x0 = x[n * 3 + 0], x1 = x[n * 3 + 1], x2 = x[n * 3 + 2];
    float tx = 0.f, ty = 0.f, tz = 0.f;
    for (int i = s + lid; i < e; i += 64){
        int eid = perm[i];
        int c = col[eid];
        float d0 = x0 - x[c * 3 + 0];
        float d1 = x1 - x[c * 3 + 1];
        float d2 = x2 - x[c * 3 + 2];
        float r2 = d0 * d0 + d1 * d1 + d2 * d2;
        float f  = phi[i] / (sqrtf(r2 + 1e-8f) + 1.f);   // NORM_CONST = 1
        tx += d0 * f; ty += d1 * f; tz += d2 * f;
    }
    for (int o = 32; o; o >>= 1){
        tx += __shfl_down(tx, o);
        ty += __shfl_down(ty, o);
        tz += __shfl_down(tz, o);
    }
    if (lid == 0){
        xout[n * 3 + 0] = x0 + 0.01f * tx;
        xout[n * 3 + 1] = x1 + 0.01f * ty;
        xout[n * 3 + 2] = x2 + 0.01f * tz;
    }
}

// ---------------------------------------------------------------------------
extern "C" void kernel_launch(void* const* d_in, const int* in_sizes, int n_in,
                              void* d_out, int out_size, void* d_ws, size_t ws_size,
                              hipStream_t stream){
    const float* h  = (const float*)d_in[0];
    const float* x  = (const float*)d_in[1];
    const int*   ei = (const int*)d_in[2];
    const float* ea = (const float*)d_in[3];
    const int* rowp = ei;
    const int* colp = ei + NE;

    const float* ew1[2] = {(const float*)d_in[4],  (const float*)d_in[14]};
    const float* eb1[2] = {(const float*)d_in[5],  (const float*)d_in[15]};
    const float* ew2[2] = {(const float*)d_in[6],  (const float*)d_in[16]};
    const float* eb2[2] = {(const float*)d_in[7],  (const float*)d_in[17]};
    const float* nw1[2] = {(const float*)d_in[8],  (const float*)d_in[18]};
    const float* nb1[2] = {(const float*)d_in[9],  (const float*)d_in[19]};
    const float* nw2[2] = {(const float*)d_in[10], (const float*)d_in[20]};
    const float* nb2[2] = {(const float*)d_in[11], (const float*)d_in[21]};
    const float* aw[2]  = {(const float*)d_in[12], (const float*)d_in[22]};
    const float* ab[2]  = {(const float*)d_in[13], (const float*)d_in[23]};
    const float* cw1 = (const float*)d_in[24];
    const float* cb1 = (const float*)d_in[25];
    const float* cw2 = (const float*)d_in[26];
    const float* cb2 = (const float*)d_in[27];
    const float* cw3 = (const float*)d_in[28];

    char* w = (char*)d_ws;
    auto alloc = [&](size_t bytes){ void* p = (void*)w; w += (bytes + 255) & ~((size_t)255); return p; };
    int* rs    = (int*)alloc((NN + 1) * sizeof(int));
    int* cur   = (int*)alloc(NN * sizeof(int));
    int* perm  = (int*)alloc(NE * sizeof(int));
    __half* HrowB = (__half*)alloc((size_t)NN * HID * sizeof(__half));
    __half* HcolB = (__half*)alloc((size_t)NN * HID * sizeof(__half));
    float*  aggb  = (float*)alloc((size_t)NN * HID * sizeof(float));
    __half* wfrag = (__half*)alloc((size_t)15 * HID * HID * sizeof(__half));
    float*  phi   = (float*)alloc((size_t)NE * sizeof(float));
    __half* h16   = (__half*)alloc((size_t)NN * HID * sizeof(__half));
    __half* Tb16  = HrowB;   // HrowB dead after edge kernel; reuse for node-MLP hidden

    float* hout = (float*)d_out;            // [NN,HID]
    float* xout = hout + (size_t)NN * HID;  // [NN,3]

    // CSR build + conversions
    hipMemsetAsync(cur, 0, NN * sizeof(int), stream);
    k_count<<<(NE + 255) / 256, 256, 0, stream>>>(rowp, cur);
    k_scan<<<1, 256, 0, stream>>>(cur, rs, cur);
    k_fill<<<(NE + 255) / 256, 256, 0, stream>>>(rowp, cur, perm);

    CvtPtrs cp;
    for (int l = 0; l < 2; l++){
        cp.p[l * 5 + 0] = ew1[l];
        cp.p[l * 5 + 1] = ew1[l] + 256 * HID;
        cp.p[l * 5 + 2] = nw1[l];
        cp.p[l * 5 + 3] = nw1[l] + 256 * HID;
        cp.p[l * 5 + 4] = nw2[l];
    }
    cp.p[10] = cw1;
    cp.p[11] = cw1 + 256 * HID;
    cp.p[12] = ew2[0];
    cp.p[13] = ew2[1];
    cp.p[14] = cw2;
    k_cvtw<<<15 * 256, 256, 0, stream>>>(cp, wfrag);
    k_cvt16<<<1250, 256, 0, stream>>>(h, h16);

    dim3 g2(157, 2), g4(157, 4);
    const float* hres = h;
    for (int l = 0; l < 2; l++){
        // [Hrow|Hcol] = h@[ew1a|ew1b] (+eb1 on first half), fp16 outs, one dispatch
        k_dgemm<<<g4, 256, 0, stream>>>(h16, nullptr, wfrag, l * 5 + 0, l * 5 + 1,
                                        eb1[l], nullptr, nullptr, HrowB, HcolB, DG_SPLIT, 0);
        hipMemsetAsync(aggb, 0, (size_t)NN * HID * sizeof(float), stream);
        k_edge_mfma<<<NEB, 256, 0, stream>>>(HrowB, HcolB, rowp, colp, ea, perm,
                                             wfrag + (size_t)(12 + l) * HID * HID,
                                             ew1[l] + 512 * HID, ew1[l] + 513 * HID,
                                             eb2[l], aw[l], ab[l], aggb);
        // T = silu(h@nw1a + agg@nw1b + nb1)  -> fp16
        k_dgemm<<<g2, 256, 0, stream>>>(h16, aggb, wfrag, l * 5 + 2, l * 5 + 3,
                                        nb1[l], nullptr, nullptr, Tb16, nullptr, DG_2A, 1);
        // h = hres + T@nw2 + nb2  -> fp32 (d_out) + fp16 mirror
        k_dgemm<<<g2, 256, 0, stream>>>(Tb16, nullptr, wfrag, l * 5 + 4, 0,
                                        nb2[l], hres, hout, h16, nullptr, DG_PLAIN, 0);
        hres = hout;
    }
    // coord update
    k_dgemm<<<g4, 256, 0, stream>>>(h16, nullptr, wfrag, 10, 11,
                                    cb1, nullptr, nullptr, HrowB, HcolB, DG_SPLIT, 0);
    k_coord_mfma<<<NEB, 256, 0, stream>>>(HrowB, HcolB, rowp, colp, ea, perm,
                                          wfrag + (size_t)14 * HID * HID,
                                          cw1 + 512 * HID, cw1 + 513 * HID,
                                          cb2, cw3, phi);
    k_xupd<<<NN, 64, 0, stream>>>(x, phi, colp, perm, rs, xout);
}